// Round 2
// baseline (6185.749 us; speedup 1.0000x reference)
//
#include <hip/hip_runtime.h>
#include <hip/hip_fp16.h>
#include <math.h>

#define TOK  1024
#define DIMK 4096
#define HID  11008

#define BT 64
#define BN 64
#define BK 64
#define LDST 68   // padded LDS stride (ints): breaks pow2 bank alignment, keeps 16B alignment

typedef long long ll;

// One exact MAC: both operands known to fit in signed 24 bits -> v_mad_i32_i24.
__device__ __forceinline__ int mad24(int a, int b, int c) {
  return ((a << 8) >> 8) * ((b << 8) >> 8) + c;
}

// Gate path, replicating per-op fp16 rounding (numpy f16 ufuncs / XLA f16 HLO
// with LLVM half->float promotion). All |g| < 2048 here so f16(g/65536) is
// exact, and all intermediates stay in f16-normal range:
//   v   = g / 65536                      (exact f16/f32)
//   e16 = f16( exp_f32(-v) )             (CR f32 exp via f64, then RN to f16)
//   d16 = f16( 1 + e16 )                 (1+e16 is exact in f32; single RN to f16)
//   s16 = f16( 1.0f / d16 )              (f32 CR divide, then RN to f16)
//   p16 = f16( v * s16 )                 (product of two f16 exact in f32)
//   out = round_half_even(p16 * 65536)   (exact f32 scale, RNE to int)
__device__ __forceinline__ int gate_requant(int g) {
  const float vf = __half2float(__float2half((float)g * (1.0f / 65536.0f)));
  const float e32 = (float)exp(-(double)vf);
  const float e16 = __half2float(__float2half(e32));
  const float d16 = __half2float(__float2half(1.0f + e16));
  const float s16 = __half2float(__float2half(1.0f / d16));
  const float p16 = __half2float(__float2half(vf * s16));
  return __float2int_rn(p16 * 65536.0f);
}

// Up projection: t13[t,h] for a 64x64 tile. Computes BOTH x@w1i^T and x@w3i^T
// (shared A operand), then the full gate/requant epilogue. Weights are
// quantized on the fly while staging into LDS (rn = half-even, exact).
__global__ __launch_bounds__(256)
void ffn_up(const int* __restrict__ x, const float* __restrict__ w1,
            const float* __restrict__ w3, short* __restrict__ t13)
{
  __shared__ int As[BT][LDST];
  __shared__ int B1[BK][LDST];
  __shared__ int B3[BK][LDST];

  const int tx = threadIdx.x, ty = threadIdx.y;
  const int tid = ty * 16 + tx;
  const int col0 = blockIdx.x * BN;   // over HID
  const int row0 = blockIdx.y * BT;   // over TOK
  const int lr = tid >> 4;            // 0..15
  const int lk = (tid & 15) << 2;     // 0,4,...,60

  int acc1[16] = {0};
  int acc3[16] = {0};

  for (int k0 = 0; k0 < DIMK; k0 += BK) {
    #pragma unroll
    for (int m = 0; m < 4; ++m) {
      const int r = lr + m * 16;
      // stage x tile (row-major) — 16B coalesced
      *reinterpret_cast<int4*>(&As[r][lk]) =
          *reinterpret_cast<const int4*>(&x[(size_t)(row0 + r) * DIMK + k0 + lk]);
      // stage w1/w3 tiles transposed [k][j], quantizing f32 -> int fixed point
      const float4 f1 = *reinterpret_cast<const float4*>(&w1[(size_t)(col0 + r) * DIMK + k0 + lk]);
      const float4 f3 = *reinterpret_cast<const float4*>(&w3[(size_t)(col0 + r) * DIMK + k0 + lk]);
      B1[lk + 0][r] = __float2int_rn(f1.x * 65536.0f);
      B1[lk + 1][r] = __float2int_rn(f1.y * 65536.0f);
      B1[lk + 2][r] = __float2int_rn(f1.z * 65536.0f);
      B1[lk + 3][r] = __float2int_rn(f1.w * 65536.0f);
      B3[lk + 0][r] = __float2int_rn(f3.x * 65536.0f);
      B3[lk + 1][r] = __float2int_rn(f3.y * 65536.0f);
      B3[lk + 2][r] = __float2int_rn(f3.z * 65536.0f);
      B3[lk + 3][r] = __float2int_rn(f3.w * 65536.0f);
    }
    __syncthreads();
    #pragma unroll 8
    for (int kk = 0; kk < BK; ++kk) {
      const int4 b1 = *reinterpret_cast<const int4*>(&B1[kk][tx << 2]);
      const int4 b3 = *reinterpret_cast<const int4*>(&B3[kk][tx << 2]);
      #pragma unroll
      for (int i = 0; i < 4; ++i) {
        const int av = As[(ty << 2) + i][kk] & 255;  // x in [0,255]: informs i24
        acc1[i*4+0] = mad24(av, b1.x, acc1[i*4+0]);
        acc1[i*4+1] = mad24(av, b1.y, acc1[i*4+1]);
        acc1[i*4+2] = mad24(av, b1.z, acc1[i*4+2]);
        acc1[i*4+3] = mad24(av, b1.w, acc1[i*4+3]);
        acc3[i*4+0] = mad24(av, b3.x, acc3[i*4+0]);
        acc3[i*4+1] = mad24(av, b3.y, acc3[i*4+1]);
        acc3[i*4+2] = mad24(av, b3.z, acc3[i*4+2]);
        acc3[i*4+3] = mad24(av, b3.w, acc3[i*4+3]);
      }
    }
    __syncthreads();
  }

  #pragma unroll
  for (int i = 0; i < 4; ++i) {
    #pragma unroll
    for (int j = 0; j < 4; ++j) {
      const int g    = (acc1[i*4+j] + 32768) >> 16;   // floor-div by 2^16
      const int q3   = (acc3[i*4+j] + 32768) >> 16;
      const int gate = gate_requant(g);
      const int tv = (int)(((ll)gate * (ll)q3 + 32768) >> 16);
      t13[(size_t)(row0 + (ty<<2) + i) * HID + col0 + (tx<<2) + j] = (short)tv;
    }
  }
}

// Down projection: out[t,d] = (t13 @ w2i^T + 2^15) >> 16
__global__ __launch_bounds__(256)
void ffn_down(const short* __restrict__ t13, const float* __restrict__ w2,
              int* __restrict__ out)
{
  __shared__ int As[BT][LDST];
  __shared__ int Bs[BK][LDST];

  const int tx = threadIdx.x, ty = threadIdx.y;
  const int tid = ty * 16 + tx;
  const int col0 = blockIdx.x * BN;   // over DIM
  const int row0 = blockIdx.y * BT;   // over TOK
  const int lr = tid >> 4;            // 0..15
  const int lk = (tid & 15) << 2;     // 0,4,...,60
  const int ar = tid >> 3;            // 0..31
  const int ak = (tid & 7) << 3;      // 0,8,...,56

  int acc[16] = {0};

  for (int k0 = 0; k0 < HID; k0 += BK) {   // 172 iterations
    #pragma unroll
    for (int m = 0; m < 2; ++m) {
      const int r = ar + m * 32;
      const int4 v = *reinterpret_cast<const int4*>(&t13[(size_t)(row0 + r) * HID + k0 + ak]);
      As[r][ak+0] = (v.x << 16) >> 16;  As[r][ak+1] = v.x >> 16;
      As[r][ak+2] = (v.y << 16) >> 16;  As[r][ak+3] = v.y >> 16;
      As[r][ak+4] = (v.z << 16) >> 16;  As[r][ak+5] = v.z >> 16;
      As[r][ak+6] = (v.w << 16) >> 16;  As[r][ak+7] = v.w >> 16;
    }
    #pragma unroll
    for (int m = 0; m < 4; ++m) {
      const int r = lr + m * 16;
      const float4 f = *reinterpret_cast<const float4*>(&w2[(size_t)(col0 + r) * HID + k0 + lk]);
      Bs[lk + 0][r] = __float2int_rn(f.x * 65536.0f);
      Bs[lk + 1][r] = __float2int_rn(f.y * 65536.0f);
      Bs[lk + 2][r] = __float2int_rn(f.z * 65536.0f);
      Bs[lk + 3][r] = __float2int_rn(f.w * 65536.0f);
    }
    __syncthreads();
    #pragma unroll 8
    for (int kk = 0; kk < BK; ++kk) {
      const int4 b = *reinterpret_cast<const int4*>(&Bs[kk][tx << 2]);
      #pragma unroll
      for (int i = 0; i < 4; ++i) {
        const int av = As[(ty << 2) + i][kk];   // |t13| small, fits i24
        acc[i*4+0] = mad24(av, b.x, acc[i*4+0]);
        acc[i*4+1] = mad24(av, b.y, acc[i*4+1]);
        acc[i*4+2] = mad24(av, b.z, acc[i*4+2]);
        acc[i*4+3] = mad24(av, b.w, acc[i*4+3]);
      }
    }
    __syncthreads();
  }

  #pragma unroll
  for (int i = 0; i < 4; ++i) {
    #pragma unroll
    for (int j = 0; j < 4; ++j) {
      out[(size_t)(row0 + (ty<<2) + i) * DIMK + col0 + (tx<<2) + j] =
          (acc[i*4+j] + 32768) >> 16;
    }
  }
}

extern "C" void kernel_launch(void* const* d_in, const int* in_sizes, int n_in,
                              void* d_out, int out_size, void* d_ws, size_t ws_size,
                              hipStream_t stream) {
  (void)in_sizes; (void)n_in; (void)out_size;
  const int*   x  = (const int*)d_in[0];
  const float* w1 = (const float*)d_in[1];
  const float* w2 = (const float*)d_in[2];
  const float* w3 = (const float*)d_in[3];
  int* out = (int*)d_out;
  short* t13 = (short*)d_ws;
  if (ws_size < (size_t)TOK * HID * sizeof(short)) return;  // need 22.5 MB scratch

  dim3 blk(16, 16);
  dim3 g1(HID / BN, TOK / BT);    // 172 x 16
  dim3 g2(DIMK / BN, TOK / BT);   // 64 x 16
  hipLaunchKernelGGL(ffn_up,   g1, blk, 0, stream, x, w1, w3, t13);
  hipLaunchKernelGGL(ffn_down, g2, blk, 0, stream, t13, w2, out);
}

// Round 3
// 695.286 us; speedup vs baseline: 8.8967x; 8.8967x over previous
//
#include <hip/hip_runtime.h>
#include <hip/hip_fp16.h>
#include <math.h>

#define TOK  1024
#define DIMK 4096
#define HID  11008

typedef long long ll;
typedef int v4i  __attribute__((ext_vector_type(4)));
typedef int v16i __attribute__((ext_vector_type(16)));

// ---------- ws layout ----------
#define T13_OFF 0ull
#define T13_SZ  ((size_t)TOK * HID)                 // 11,272,192  (i8 t13)
#define LUT_OFF 11272192ull
#define CS1_OFF (LUT_OFF + 32768ull)
#define CS3_OFF (CS1_OFF + 44032ull)
#define XQ_OFF  (CS3_OFF + 44032ull)
#define WQ_OFF  (XQ_OFF + 4194304ull)
#define PLANE   45088768ull                          // 11008*4096 bytes
#define WS_NEED (WQ_OFF + 6ull * PLANE)              // ~273 MB

// ---------- exact fp16-silu requant (proven in round 2) ----------
__device__ __forceinline__ int gate_requant(int g) {
  const float vf = __half2float(__float2half((float)g * (1.0f / 65536.0f)));
  const float e32 = (float)exp(-(double)vf);
  const float e16 = __half2float(__float2half(e32));
  const float d16 = __half2float(__float2half(1.0f + e16));
  const float s16 = __half2float(__float2half(1.0f / d16));
  const float p16 = __half2float(__float2half(vf * s16));
  return __float2int_rn(p16 * 65536.0f);
}

__device__ __forceinline__ v16i vzero16() {
  v16i z;
  #pragma unroll
  for (int i = 0; i < 16; ++i) z[i] = 0;
  return z;
}

// async global->LDS, 16B per lane; lds ptr must be wave-uniform
__device__ __forceinline__ void gll(const void* g, void* l) {
  __builtin_amdgcn_global_load_lds((const __attribute__((address_space(1))) unsigned int*)g,
                                   (__attribute__((address_space(3))) unsigned int*)l,
                                   16, 0, 0);
}

// ============================================================
// Pre-pass kernels
// ============================================================

__global__ void lut_kernel(int* __restrict__ lut) {
  const int i = blockIdx.x * blockDim.x + threadIdx.x;   // 0..8191
  lut[i] = gate_requant(i - 4096);
}

// xq = (i8)(x - 128), packed bytes
__global__ __launch_bounds__(256)
void xq_kernel(const int* __restrict__ x, char* __restrict__ xq) {
  const size_t base = ((size_t)blockIdx.x * 256 + threadIdx.x) * 16;
  int w[4];
  #pragma unroll
  for (int i = 0; i < 4; ++i) {
    const int4 v = *reinterpret_cast<const int4*>(&x[base + i * 4]);
    w[i] = ((v.x & 255) | ((v.y & 255) << 8) | ((v.z & 255) << 16) | ((v.w & 255) << 24)) ^ 0x80808080;
  }
  *reinterpret_cast<int4*>(&xq[base]) = make_int4(w[0], w[1], w[2], w[3]);
}

// quantize f32 weights -> lo/hi i8 planes (+ optional integer colsum)
__global__ __launch_bounds__(256)
void prequant(const float* __restrict__ src, char* __restrict__ lo, char* __restrict__ hi,
              int* __restrict__ csum, int R, int K, int nchunks)
{
  const int wid = blockIdx.x * 4 + (threadIdx.x >> 6);
  const int lane = threadIdx.x & 63;
  const int row = wid / nchunks;
  const int ck  = wid - row * nchunks;
  const int k0  = ck * 1024 + lane * 16;
  int sum = 0;
  if (k0 < K) {
    const size_t base = (size_t)row * K + k0;
    int lob[4], hib[4];
    #pragma unroll
    for (int i = 0; i < 4; ++i) {
      const float4 f = *reinterpret_cast<const float4*>(&src[base + i * 4]);
      const int q0 = __float2int_rn(f.x * 65536.0f);
      const int q1 = __float2int_rn(f.y * 65536.0f);
      const int q2 = __float2int_rn(f.z * 65536.0f);
      const int q3 = __float2int_rn(f.w * 65536.0f);
      sum += q0 + q1 + q2 + q3;
      lob[i] = (q0 & 127) | ((q1 & 127) << 8) | ((q2 & 127) << 16) | ((q3 & 127) << 24);
      hib[i] = ((q0 >> 7) & 255) | (((q1 >> 7) & 255) << 8) | (((q2 >> 7) & 255) << 16) | (((q3 >> 7) & 255) << 24);
    }
    *reinterpret_cast<int4*>(&lo[base]) = make_int4(lob[0], lob[1], lob[2], lob[3]);
    *reinterpret_cast<int4*>(&hi[base]) = make_int4(hib[0], hib[1], hib[2], hib[3]);
  }
  if (csum) {   // only used when K%1024==0 -> all lanes active
    #pragma unroll
    for (int off = 32; off > 0; off >>= 1) sum += __shfl_xor(sum, off, 64);
    if (lane == 0) atomicAdd(&csum[row], sum);
  }
}

// ============================================================
// Up GEMM: c=(x-128) @ {w1,w3}^T in i8 MFMA, fused silu-gate epilogue
// BT=128 rows, BN=64 cols, BK=64; 512 thr = 8 waves (4 rowfrag x 2 colfrag)
// LDS fragment-order: A[ks][rf][lane][16B], B[plane][ks][cf][lane][16B]
// ============================================================
#define UP_BUF 24576

__global__ __launch_bounds__(512, 1)
void up_gemm(const char* __restrict__ xq, const char* __restrict__ wq,
             const int* __restrict__ csum1, const int* __restrict__ csum3,
             const int* __restrict__ lut, char* __restrict__ t13)
{
  __shared__ char smem[2 * UP_BUF];
  const int tid = threadIdx.x;
  const int w = tid >> 6, l = tid & 63;
  const int rf = w & 3, cf = w >> 2;          // compute roles
  const int row0 = blockIdx.x * 128;
  const int col0 = blockIdx.y * 64;

  // staging roles: wave w loads A-segment (ks=w&1, rf=w>>1) and B-segments bid=2w,2w+1
  const int sks = w & 1, srf = w >> 1;
  const char* gA = xq + (size_t)(row0 + srf * 32 + (l & 31)) * DIMK + sks * 32 + (l >> 5) * 16;
  const int bid0 = 2 * w, bid1 = 2 * w + 1;   // bid = plane*4 + ks*2 + cf
  const char* gB0 = wq + (size_t)(bid0 >> 2) * PLANE
      + (size_t)(col0 + (bid0 & 1) * 32 + (l & 31)) * DIMK + ((bid0 >> 1) & 1) * 32 + (l >> 5) * 16;
  const char* gB1 = wq + (size_t)(bid1 >> 2) * PLANE
      + (size_t)(col0 + (bid1 & 1) * 32 + (l & 31)) * DIMK + ((bid1 >> 1) & 1) * 32 + (l >> 5) * 16;
  const unsigned dA  = (sks * 4 + srf) * 1024;
  const unsigned dB0 = 8192 + bid0 * 1024;
  const unsigned dB1 = 8192 + bid1 * 1024;

  v16i a00 = vzero16(), a01 = vzero16(), a10 = vzero16(), a11 = vzero16();

  // prologue
  gll(gA, smem + dA);
  gll(gB0, smem + dB0);
  gll(gB1, smem + dB1);
  __syncthreads();

  int buf = 0;
  for (int kt = 0; kt < DIMK / 64; ++kt) {
    if (kt + 1 < DIMK / 64) {
      const int kb = (kt + 1) * 64;
      const unsigned bo = (buf ^ 1) * UP_BUF;
      gll(gA + kb, smem + bo + dA);
      gll(gB0 + kb, smem + bo + dB0);
      gll(gB1 + kb, smem + bo + dB1);
    }
    const char* sb = smem + buf * UP_BUF;
    #pragma unroll
    for (int ks = 0; ks < 2; ++ks) {
      const v4i av  = *(const v4i*)(sb + (ks * 4 + rf) * 1024 + l * 16);
      const v4i b1l = *(const v4i*)(sb + 8192 + ((0 * 4) + ks * 2 + cf) * 1024 + l * 16);
      const v4i b1h = *(const v4i*)(sb + 8192 + ((1 * 4) + ks * 2 + cf) * 1024 + l * 16);
      const v4i b3l = *(const v4i*)(sb + 8192 + ((2 * 4) + ks * 2 + cf) * 1024 + l * 16);
      const v4i b3h = *(const v4i*)(sb + 8192 + ((3 * 4) + ks * 2 + cf) * 1024 + l * 16);
      a00 = __builtin_amdgcn_mfma_i32_32x32x32_i8(av, b1l, a00, 0, 0, 0);
      a01 = __builtin_amdgcn_mfma_i32_32x32x32_i8(av, b1h, a01, 0, 0, 0);
      a10 = __builtin_amdgcn_mfma_i32_32x32x32_i8(av, b3l, a10, 0, 0, 0);
      a11 = __builtin_amdgcn_mfma_i32_32x32x32_i8(av, b3h, a11, 0, 0, 0);
    }
    __syncthreads();
    buf ^= 1;
  }

  // epilogue: t1 = a00 + (a01 + csum1)<<7 ; g->lut ; t3 likewise ; t13 i8
  const int col = col0 + cf * 32 + (l & 31);
  const int cs1 = csum1[col], cs3 = csum3[col];
  #pragma unroll
  for (int r = 0; r < 16; ++r) {
    const int row = row0 + rf * 32 + (r & 3) + 8 * (r >> 2) + 4 * (l >> 5);
    const ll t1 = (ll)a00[r] + (((ll)a01[r] + cs1) << 7);
    int g = (int)((t1 + 32768) >> 16);
    g = g < -4096 ? -4096 : (g > 4095 ? 4095 : g);
    const ll t3 = (ll)a10[r] + (((ll)a11[r] + cs3) << 7);
    const int q3 = (int)((t3 + 32768) >> 16);
    const int gate = lut[g + 4096];
    const int tv = (int)(((ll)gate * q3 + 32768) >> 16);
    t13[(size_t)row * HID + col] = (char)tv;
  }
}

// ============================================================
// Down GEMM: out = (t13 @ w2^T + 2^15) >> 16 ; t13 single i8, w2 2 pieces
// BT=128, BN=64, BK=64 over HID; 512 thr = 8 waves
// ============================================================
#define DN_BUF 16384

__global__ __launch_bounds__(512, 1)
void down_gemm(const char* __restrict__ t13, const char* __restrict__ w2lo,
               const char* __restrict__ w2hi, int* __restrict__ out)
{
  __shared__ char smem[2 * DN_BUF];
  const int tid = threadIdx.x;
  const int w = tid >> 6, l = tid & 63;
  const int rf = w & 3, cf = w >> 2;
  const int row0 = blockIdx.x * 128;
  const int col0 = blockIdx.y * 64;

  // staging: wave w -> A(ks=w&1, rf=w>>1) and B bid=w (bid = p*4 + ks*2 + cf)
  const char* gA = t13 + (size_t)(row0 + (w >> 1) * 32 + (l & 31)) * HID + (w & 1) * 32 + (l >> 5) * 16;
  const char* pB = (w >> 2) ? w2hi : w2lo;
  const char* gB = pB + (size_t)(col0 + (w & 1) * 32 + (l & 31)) * HID + ((w >> 1) & 1) * 32 + (l >> 5) * 16;
  const unsigned dA = ((w & 1) * 4 + (w >> 1)) * 1024;
  const unsigned dB = 8192 + w * 1024;

  v16i accL = vzero16(), accH = vzero16();

  gll(gA, smem + dA);
  gll(gB, smem + dB);
  __syncthreads();

  int buf = 0;
  for (int kt = 0; kt < HID / 64; ++kt) {
    if (kt + 1 < HID / 64) {
      const int kb = (kt + 1) * 64;
      const unsigned bo = (buf ^ 1) * DN_BUF;
      gll(gA + kb, smem + bo + dA);
      gll(gB + kb, smem + bo + dB);
    }
    const char* sb = smem + buf * DN_BUF;
    #pragma unroll
    for (int ks = 0; ks < 2; ++ks) {
      const v4i av = *(const v4i*)(sb + (ks * 4 + rf) * 1024 + l * 16);
      const v4i bl = *(const v4i*)(sb + 8192 + (0 * 4 + ks * 2 + cf) * 1024 + l * 16);
      const v4i bh = *(const v4i*)(sb + 8192 + (1 * 4 + ks * 2 + cf) * 1024 + l * 16);
      accL = __builtin_amdgcn_mfma_i32_32x32x32_i8(av, bl, accL, 0, 0, 0);
      accH = __builtin_amdgcn_mfma_i32_32x32x32_i8(av, bh, accH, 0, 0, 0);
    }
    __syncthreads();
    buf ^= 1;
  }

  const int col = col0 + cf * 32 + (l & 31);
  #pragma unroll
  for (int r = 0; r < 16; ++r) {
    const int row = row0 + rf * 32 + (r & 3) + 8 * (r >> 2) + 4 * (l >> 5);
    const ll t = (ll)accL[r] + ((ll)accH[r] << 7);
    out[(size_t)row * DIMK + col] = (int)((t + 32768) >> 16);
  }
}

// ============================================================
// Fallback (round-2 passing VALU kernels, used if ws too small)
// ============================================================
#define BT 64
#define BN 64
#define BK 64
#define LDST 68

__device__ __forceinline__ int mad24(int a, int b, int c) {
  return ((a << 8) >> 8) * ((b << 8) >> 8) + c;
}

__global__ __launch_bounds__(256)
void ffn_up_f(const int* __restrict__ x, const float* __restrict__ w1,
              const float* __restrict__ w3, short* __restrict__ t13)
{
  __shared__ int As[BT][LDST];
  __shared__ int B1[BK][LDST];
  __shared__ int B3[BK][LDST];
  const int tx = threadIdx.x, ty = threadIdx.y;
  const int tid = ty * 16 + tx;
  const int col0 = blockIdx.x * BN;
  const int row0 = blockIdx.y * BT;
  const int lr = tid >> 4;
  const int lk = (tid & 15) << 2;
  int acc1[16] = {0};
  int acc3[16] = {0};
  for (int k0 = 0; k0 < DIMK; k0 += BK) {
    #pragma unroll
    for (int m = 0; m < 4; ++m) {
      const int r = lr + m * 16;
      *reinterpret_cast<int4*>(&As[r][lk]) =
          *reinterpret_cast<const int4*>(&x[(size_t)(row0 + r) * DIMK + k0 + lk]);
      const float4 f1 = *reinterpret_cast<const float4*>(&w1[(size_t)(col0 + r) * DIMK + k0 + lk]);
      const float4 f3 = *reinterpret_cast<const float4*>(&w3[(size_t)(col0 + r) * DIMK + k0 + lk]);
      B1[lk + 0][r] = __float2int_rn(f1.x * 65536.0f);
      B1[lk + 1][r] = __float2int_rn(f1.y * 65536.0f);
      B1[lk + 2][r] = __float2int_rn(f1.z * 65536.0f);
      B1[lk + 3][r] = __float2int_rn(f1.w * 65536.0f);
      B3[lk + 0][r] = __float2int_rn(f3.x * 65536.0f);
      B3[lk + 1][r] = __float2int_rn(f3.y * 65536.0f);
      B3[lk + 2][r] = __float2int_rn(f3.z * 65536.0f);
      B3[lk + 3][r] = __float2int_rn(f3.w * 65536.0f);
    }
    __syncthreads();
    #pragma unroll 8
    for (int kk = 0; kk < BK; ++kk) {
      const int4 b1 = *reinterpret_cast<const int4*>(&B1[kk][tx << 2]);
      const int4 b3 = *reinterpret_cast<const int4*>(&B3[kk][tx << 2]);
      #pragma unroll
      for (int i = 0; i < 4; ++i) {
        const int av = As[(ty << 2) + i][kk] & 255;
        acc1[i*4+0] = mad24(av, b1.x, acc1[i*4+0]);
        acc1[i*4+1] = mad24(av, b1.y, acc1[i*4+1]);
        acc1[i*4+2] = mad24(av, b1.z, acc1[i*4+2]);
        acc1[i*4+3] = mad24(av, b1.w, acc1[i*4+3]);
        acc3[i*4+0] = mad24(av, b3.x, acc3[i*4+0]);
        acc3[i*4+1] = mad24(av, b3.y, acc3[i*4+1]);
        acc3[i*4+2] = mad24(av, b3.z, acc3[i*4+2]);
        acc3[i*4+3] = mad24(av, b3.w, acc3[i*4+3]);
      }
    }
    __syncthreads();
  }
  #pragma unroll
  for (int i = 0; i < 4; ++i) {
    #pragma unroll
    for (int j = 0; j < 4; ++j) {
      const int g    = (acc1[i*4+j] + 32768) >> 16;
      const int q3   = (acc3[i*4+j] + 32768) >> 16;
      const int gate = gate_requant(g);
      const int tv = (int)(((ll)gate * (ll)q3 + 32768) >> 16);
      t13[(size_t)(row0 + (ty<<2) + i) * HID + col0 + (tx<<2) + j] = (short)tv;
    }
  }
}

__global__ __launch_bounds__(256)
void ffn_down_f(const short* __restrict__ t13, const float* __restrict__ w2,
                int* __restrict__ out)
{
  __shared__ int As[BT][LDST];
  __shared__ int Bs[BK][LDST];
  const int tx = threadIdx.x, ty = threadIdx.y;
  const int tid = ty * 16 + tx;
  const int col0 = blockIdx.x * BN;
  const int row0 = blockIdx.y * BT;
  const int lr = tid >> 4;
  const int lk = (tid & 15) << 2;
  const int ar = tid >> 3;
  const int ak = (tid & 7) << 3;
  int acc[16] = {0};
  for (int k0 = 0; k0 < HID; k0 += BK) {
    #pragma unroll
    for (int m = 0; m < 2; ++m) {
      const int r = ar + m * 32;
      const int4 v = *reinterpret_cast<const int4*>(&t13[(size_t)(row0 + r) * HID + k0 + ak]);
      As[r][ak+0] = (v.x << 16) >> 16;  As[r][ak+1] = v.x >> 16;
      As[r][ak+2] = (v.y << 16) >> 16;  As[r][ak+3] = v.y >> 16;
      As[r][ak+4] = (v.z << 16) >> 16;  As[r][ak+5] = v.z >> 16;
      As[r][ak+6] = (v.w << 16) >> 16;  As[r][ak+7] = v.w >> 16;
    }
    #pragma unroll
    for (int m = 0; m < 4; ++m) {
      const int r = lr + m * 16;
      const float4 f = *reinterpret_cast<const float4*>(&w2[(size_t)(col0 + r) * HID + k0 + lk]);
      Bs[lk + 0][r] = __float2int_rn(f.x * 65536.0f);
      Bs[lk + 1][r] = __float2int_rn(f.y * 65536.0f);
      Bs[lk + 2][r] = __float2int_rn(f.z * 65536.0f);
      Bs[lk + 3][r] = __float2int_rn(f.w * 65536.0f);
    }
    __syncthreads();
    #pragma unroll 8
    for (int kk = 0; kk < BK; ++kk) {
      const int4 b = *reinterpret_cast<const int4*>(&Bs[kk][tx << 2]);
      #pragma unroll
      for (int i = 0; i < 4; ++i) {
        const int av = As[(ty << 2) + i][kk];
        acc[i*4+0] = mad24(av, b.x, acc[i*4+0]);
        acc[i*4+1] = mad24(av, b.y, acc[i*4+1]);
        acc[i*4+2] = mad24(av, b.z, acc[i*4+2]);
        acc[i*4+3] = mad24(av, b.w, acc[i*4+3]);
      }
    }
    __syncthreads();
  }
  #pragma unroll
  for (int i = 0; i < 4; ++i) {
    #pragma unroll
    for (int j = 0; j < 4; ++j) {
      out[(size_t)(row0 + (ty<<2) + i) * DIMK + col0 + (tx<<2) + j] =
          (acc[i*4+j] + 32768) >> 16;
    }
  }
}

// ============================================================
extern "C" void kernel_launch(void* const* d_in, const int* in_sizes, int n_in,
                              void* d_out, int out_size, void* d_ws, size_t ws_size,
                              hipStream_t stream) {
  (void)in_sizes; (void)n_in; (void)out_size;
  const int*   x  = (const int*)d_in[0];
  const float* w1 = (const float*)d_in[1];
  const float* w2 = (const float*)d_in[2];
  const float* w3 = (const float*)d_in[3];
  int* out = (int*)d_out;
  char* ws = (char*)d_ws;

  if (ws_size >= WS_NEED) {
    char* t13 = ws + T13_OFF;
    int*  lut = (int*)(ws + LUT_OFF);
    int*  cs1 = (int*)(ws + CS1_OFF);
    int*  cs3 = (int*)(ws + CS3_OFF);
    char* xq  = ws + XQ_OFF;
    char* wq  = ws + WQ_OFF;

    hipMemsetAsync(ws + CS1_OFF, 0, 88064, stream);
    hipLaunchKernelGGL(lut_kernel, dim3(32), dim3(256), 0, stream, lut);
    hipLaunchKernelGGL(xq_kernel, dim3(1024), dim3(256), 0, stream, x, xq);
    hipLaunchKernelGGL(prequant, dim3(11008), dim3(256), 0, stream,
                       w1, wq + 0 * PLANE, wq + 1 * PLANE, cs1, HID, DIMK, 4);
    hipLaunchKernelGGL(prequant, dim3(11008), dim3(256), 0, stream,
                       w3, wq + 2 * PLANE, wq + 3 * PLANE, cs3, HID, DIMK, 4);
    hipLaunchKernelGGL(prequant, dim3(11264), dim3(256), 0, stream,
                       w2, wq + 4 * PLANE, wq + 5 * PLANE, (int*)nullptr, DIMK, HID, 11);
    hipLaunchKernelGGL(up_gemm, dim3(TOK / 128, HID / 64), dim3(512), 0, stream,
                       xq, wq, cs1, cs3, lut, t13);
    hipLaunchKernelGGL(down_gemm, dim3(TOK / 128, DIMK / 64), dim3(512), 0, stream,
                       t13, wq + 4 * PLANE, wq + 5 * PLANE, out);
  } else {
    if (ws_size < (size_t)TOK * HID * sizeof(short)) return;
    short* t13 = (short*)ws;
    dim3 blk(16, 16);
    hipLaunchKernelGGL(ffn_up_f,   dim3(HID / BN, TOK / BT), blk, 0, stream, x, w1, w3, t13);
    hipLaunchKernelGGL(ffn_down_f, dim3(DIMK / BN, TOK / BT), blk, 0, stream, t13, w2, out);
  }
}

// Round 4
// 664.586 us; speedup vs baseline: 9.3077x; 1.0462x over previous
//
#include <hip/hip_runtime.h>
#include <hip/hip_fp16.h>
#include <math.h>

#define TOK  1024
#define DIMK 4096
#define HID  11008

typedef long long ll;
typedef int v4i  __attribute__((ext_vector_type(4)));
typedef int v16i __attribute__((ext_vector_type(16)));

// ---------- ws layout ----------
#define T13_OFF 0ull
#define LUT_OFF 11272192ull
#define CS1_OFF (LUT_OFF + 32768ull)
#define CS3_OFF (CS1_OFF + 44032ull)
#define XQ_OFF  (CS3_OFF + 44032ull)
#define WQ_OFF  (XQ_OFF + 4194304ull)
#define PLANE   45088768ull                          // 11008*4096 bytes
#define WS_NEED (WQ_OFF + 6ull * PLANE)              // ~273 MB

// ---------- exact fp16-silu requant (proven in round 2) ----------
__device__ __forceinline__ int gate_requant(int g) {
  const float vf = __half2float(__float2half((float)g * (1.0f / 65536.0f)));
  const float e32 = (float)exp(-(double)vf);
  const float e16 = __half2float(__float2half(e32));
  const float d16 = __half2float(__float2half(1.0f + e16));
  const float s16 = __half2float(__float2half(1.0f / d16));
  const float p16 = __half2float(__float2half(vf * s16));
  return __float2int_rn(p16 * 65536.0f);
}

__device__ __forceinline__ v16i vzero16() {
  v16i z;
  #pragma unroll
  for (int i = 0; i < 16; ++i) z[i] = 0;
  return z;
}

// async global->LDS, 16B per lane; lds ptr must be wave-uniform
__device__ __forceinline__ void gll(const void* g, void* l) {
  __builtin_amdgcn_global_load_lds((const __attribute__((address_space(1))) unsigned int*)g,
                                   (__attribute__((address_space(3))) unsigned int*)l,
                                   16, 0, 0);
}

// ============================================================
// Pre-pass kernels
// ============================================================

__global__ void lut_kernel(int* __restrict__ lut) {
  const int i = blockIdx.x * blockDim.x + threadIdx.x;   // 0..8191
  lut[i] = gate_requant(i - 4096);
}

// xq = (i8)(x - 128), packed bytes
__global__ __launch_bounds__(256)
void xq_kernel(const int* __restrict__ x, char* __restrict__ xq) {
  const size_t base = ((size_t)blockIdx.x * 256 + threadIdx.x) * 16;
  int w[4];
  #pragma unroll
  for (int i = 0; i < 4; ++i) {
    const int4 v = *reinterpret_cast<const int4*>(&x[base + i * 4]);
    w[i] = ((v.x & 255) | ((v.y & 255) << 8) | ((v.z & 255) << 16) | ((v.w & 255) << 24)) ^ 0x80808080;
  }
  *reinterpret_cast<int4*>(&xq[base]) = make_int4(w[0], w[1], w[2], w[3]);
}

// All three weight matrices in one dispatch. Block = 4096 contiguous floats.
// blocks 0..11007 -> w1 (one row each), 11008..22015 -> w3, 22016..33023 -> w2.
// Fully coalesced: thread t handles float4 indices {t, t+256, t+512, t+768}
// within the block's 1024-float4 span; lo/hi stores are 4B coalesced.
__global__ __launch_bounds__(256)
void prequant_all(const float* __restrict__ w1, const float* __restrict__ w3,
                  const float* __restrict__ w2, char* __restrict__ wq,
                  int* __restrict__ cs1, int* __restrict__ cs3)
{
  const int bid = blockIdx.x;
  const int m = bid / 11008;            // 0,1,2 (uniform per block)
  const int rb = bid - m * 11008;
  const float* src = (m == 0) ? w1 : ((m == 1) ? w3 : w2);
  int* lo = (int*)(wq + (size_t)(2 * m) * PLANE);
  int* hi = (int*)(wq + (size_t)(2 * m + 1) * PLANE);
  const size_t f4base = (size_t)rb * 1024;   // float4 index base within matrix

  int sum = 0;
  #pragma unroll
  for (int j = 0; j < 4; ++j) {
    const size_t f4 = f4base + threadIdx.x + j * 256;
    const float4 f = *reinterpret_cast<const float4*>(&src[f4 * 4]);
    const int q0 = __float2int_rn(f.x * 65536.0f);
    const int q1 = __float2int_rn(f.y * 65536.0f);
    const int q2 = __float2int_rn(f.z * 65536.0f);
    const int q3 = __float2int_rn(f.w * 65536.0f);
    sum += q0 + q1 + q2 + q3;
    lo[f4] = (q0 & 127) | ((q1 & 127) << 8) | ((q2 & 127) << 16) | ((q3 & 127) << 24);
    hi[f4] = ((q0 >> 7) & 255) | (((q1 >> 7) & 255) << 8) |
             (((q2 >> 7) & 255) << 16) | (((q3 >> 7) & 255) << 24);
  }
  if (m < 2) {   // block == one 4096-elem row of w1/w3 -> integer colsum
    #pragma unroll
    for (int off = 32; off > 0; off >>= 1) sum += __shfl_xor(sum, off, 64);
    if ((threadIdx.x & 63) == 0) atomicAdd(((m == 0) ? cs1 : cs3) + rb, sum);
  }
}

// ============================================================
// Up GEMM: c=(x-128) @ {w1,w3}^T in i8 MFMA, fused silu-gate epilogue
// BT=128 rows, BN=64 cols, BK=64; 512 thr = 8 waves (4 rowfrag x 2 colfrag)
// Triple-buffered LDS, counted vmcnt (3 loads/wave/tile), raw barriers.
// ============================================================
#define UP_BUF 24576

__global__ __launch_bounds__(512, 1)
void up_gemm(const char* __restrict__ xq, const char* __restrict__ wq,
             const int* __restrict__ csum1, const int* __restrict__ csum3,
             const int* __restrict__ lut, char* __restrict__ t13)
{
  __shared__ char smem[3 * UP_BUF];
  const int tid = threadIdx.x;
  const int w = tid >> 6, l = tid & 63;
  const int rf = w & 3, cf = w >> 2;          // compute roles
  const int row0 = blockIdx.x * 128;
  const int col0 = blockIdx.y * 64;

  // staging roles: wave w loads A-segment (ks=w&1, rf=w>>1) and B-segments bid=2w,2w+1
  const int sks = w & 1, srf = w >> 1;
  const char* gA = xq + (size_t)(row0 + srf * 32 + (l & 31)) * DIMK + sks * 32 + (l >> 5) * 16;
  const int bid0 = 2 * w, bid1 = 2 * w + 1;   // bid = plane*4 + ks*2 + cf
  const char* gB0 = wq + (size_t)(bid0 >> 2) * PLANE
      + (size_t)(col0 + (bid0 & 1) * 32 + (l & 31)) * DIMK + ((bid0 >> 1) & 1) * 32 + (l >> 5) * 16;
  const char* gB1 = wq + (size_t)(bid1 >> 2) * PLANE
      + (size_t)(col0 + (bid1 & 1) * 32 + (l & 31)) * DIMK + ((bid1 >> 1) & 1) * 32 + (l >> 5) * 16;
  const unsigned dA  = (sks * 4 + srf) * 1024;
  const unsigned dB0 = 8192 + bid0 * 1024;
  const unsigned dB1 = 8192 + bid1 * 1024;

  v16i a00 = vzero16(), a01 = vzero16(), a10 = vzero16(), a11 = vzero16();

  // prologue: stage tiles 0 and 1
  gll(gA, smem + dA);  gll(gB0, smem + dB0);  gll(gB1, smem + dB1);
  gll(gA + 64, smem + UP_BUF + dA);
  gll(gB0 + 64, smem + UP_BUF + dB0);
  gll(gB1 + 64, smem + UP_BUF + dB1);

  const int NT = DIMK / 64;
  unsigned co = 0, so = 2 * UP_BUF;
  for (int kt = 0; kt < NT; ++kt) {
    if (kt + 2 < NT) {
      const int kb = (kt + 2) * 64;
      gll(gA + kb, smem + so + dA);
      gll(gB0 + kb, smem + so + dB0);
      gll(gB1 + kb, smem + so + dB1);
      so = (so == 2 * UP_BUF) ? 0 : so + UP_BUF;
      asm volatile("s_waitcnt vmcnt(6)" ::: "memory");   // tile kt landed; 6 in flight
    } else if (kt + 1 < NT) {
      asm volatile("s_waitcnt vmcnt(3)" ::: "memory");
    } else {
      asm volatile("s_waitcnt vmcnt(0)" ::: "memory");
    }
    __builtin_amdgcn_s_barrier();
    const char* sb = smem + co;
    __builtin_amdgcn_s_setprio(1);
    #pragma unroll
    for (int ks = 0; ks < 2; ++ks) {
      const v4i av  = *(const v4i*)(sb + (ks * 4 + rf) * 1024 + l * 16);
      const v4i b1l = *(const v4i*)(sb + 8192 + ((0 * 4) + ks * 2 + cf) * 1024 + l * 16);
      const v4i b1h = *(const v4i*)(sb + 8192 + ((1 * 4) + ks * 2 + cf) * 1024 + l * 16);
      const v4i b3l = *(const v4i*)(sb + 8192 + ((2 * 4) + ks * 2 + cf) * 1024 + l * 16);
      const v4i b3h = *(const v4i*)(sb + 8192 + ((3 * 4) + ks * 2 + cf) * 1024 + l * 16);
      a00 = __builtin_amdgcn_mfma_i32_32x32x32_i8(av, b1l, a00, 0, 0, 0);
      a01 = __builtin_amdgcn_mfma_i32_32x32x32_i8(av, b1h, a01, 0, 0, 0);
      a10 = __builtin_amdgcn_mfma_i32_32x32x32_i8(av, b3l, a10, 0, 0, 0);
      a11 = __builtin_amdgcn_mfma_i32_32x32x32_i8(av, b3h, a11, 0, 0, 0);
    }
    __builtin_amdgcn_s_setprio(0);
    __builtin_amdgcn_s_barrier();
    co = (co == 2 * UP_BUF) ? 0 : co + UP_BUF;
  }

  // epilogue: t1 = a00 + (a01 + csum1)<<7 ; g->lut ; t3 likewise ; t13 i8
  const int col = col0 + cf * 32 + (l & 31);
  const int cs1 = csum1[col], cs3 = csum3[col];
  #pragma unroll
  for (int r = 0; r < 16; ++r) {
    const int row = row0 + rf * 32 + (r & 3) + 8 * (r >> 2) + 4 * (l >> 5);
    const ll t1 = (ll)a00[r] + (((ll)a01[r] + cs1) << 7);
    int g = (int)((t1 + 32768) >> 16);
    g = g < -4096 ? -4096 : (g > 4095 ? 4095 : g);
    const ll t3 = (ll)a10[r] + (((ll)a11[r] + cs3) << 7);
    const int q3 = (int)((t3 + 32768) >> 16);
    const int gate = lut[g + 4096];
    const int tv = (int)(((ll)gate * q3 + 32768) >> 16);
    t13[(size_t)row * HID + col] = (char)tv;
  }
}

// ============================================================
// Down GEMM: out = (t13 @ w2^T + 2^15) >> 16 ; t13 single i8, w2 2 pieces
// BT=128, BN=64, BK=64 over HID; triple-buffer, counted vmcnt (2 loads/wave)
// ============================================================
#define DN_BUF 16384

__global__ __launch_bounds__(512, 1)
void down_gemm(const char* __restrict__ t13, const char* __restrict__ w2lo,
               const char* __restrict__ w2hi, int* __restrict__ out)
{
  __shared__ char smem[3 * DN_BUF];
  const int tid = threadIdx.x;
  const int w = tid >> 6, l = tid & 63;
  const int rf = w & 3, cf = w >> 2;
  const int row0 = blockIdx.x * 128;
  const int col0 = blockIdx.y * 64;

  // staging: wave w -> A(ks=w&1, rf=w>>1) and B bid=w (bid = p*4 + ks*2 + cf)
  const char* gA = t13 + (size_t)(row0 + (w >> 1) * 32 + (l & 31)) * HID + (w & 1) * 32 + (l >> 5) * 16;
  const char* pB = (w >> 2) ? w2hi : w2lo;
  const char* gB = pB + (size_t)(col0 + (w & 1) * 32 + (l & 31)) * HID + ((w >> 1) & 1) * 32 + (l >> 5) * 16;
  const unsigned dA = ((w & 1) * 4 + (w >> 1)) * 1024;
  const unsigned dB = 8192 + w * 1024;

  v16i accL = vzero16(), accH = vzero16();

  gll(gA, smem + dA);           gll(gB, smem + dB);
  gll(gA + 64, smem + DN_BUF + dA);
  gll(gB + 64, smem + DN_BUF + dB);

  const int NT = HID / 64;
  unsigned co = 0, so = 2 * DN_BUF;
  for (int kt = 0; kt < NT; ++kt) {
    if (kt + 2 < NT) {
      const int kb = (kt + 2) * 64;
      gll(gA + kb, smem + so + dA);
      gll(gB + kb, smem + so + dB);
      so = (so == 2 * DN_BUF) ? 0 : so + DN_BUF;
      asm volatile("s_waitcnt vmcnt(4)" ::: "memory");
    } else if (kt + 1 < NT) {
      asm volatile("s_waitcnt vmcnt(2)" ::: "memory");
    } else {
      asm volatile("s_waitcnt vmcnt(0)" ::: "memory");
    }
    __builtin_amdgcn_s_barrier();
    const char* sb = smem + co;
    __builtin_amdgcn_s_setprio(1);
    #pragma unroll
    for (int ks = 0; ks < 2; ++ks) {
      const v4i av = *(const v4i*)(sb + (ks * 4 + rf) * 1024 + l * 16);
      const v4i bl = *(const v4i*)(sb + 8192 + (0 * 4 + ks * 2 + cf) * 1024 + l * 16);
      const v4i bh = *(const v4i*)(sb + 8192 + (1 * 4 + ks * 2 + cf) * 1024 + l * 16);
      accL = __builtin_amdgcn_mfma_i32_32x32x32_i8(av, bl, accL, 0, 0, 0);
      accH = __builtin_amdgcn_mfma_i32_32x32x32_i8(av, bh, accH, 0, 0, 0);
    }
    __builtin_amdgcn_s_setprio(0);
    __builtin_amdgcn_s_barrier();
    co = (co == 2 * DN_BUF) ? 0 : co + DN_BUF;
  }

  const int col = col0 + cf * 32 + (l & 31);
  #pragma unroll
  for (int r = 0; r < 16; ++r) {
    const int row = row0 + rf * 32 + (r & 3) + 8 * (r >> 2) + 4 * (l >> 5);
    const ll t = (ll)accL[r] + ((ll)accH[r] << 7);
    out[(size_t)row * DIMK + col] = (int)((t + 32768) >> 16);
  }
}

// ============================================================
// Fallback (round-2 passing VALU kernels, used if ws too small)
// ============================================================
#define BT 64
#define BN 64
#define BK 64
#define LDST 68

__device__ __forceinline__ int mad24(int a, int b, int c) {
  return ((a << 8) >> 8) * ((b << 8) >> 8) + c;
}

__global__ __launch_bounds__(256)
void ffn_up_f(const int* __restrict__ x, const float* __restrict__ w1,
              const float* __restrict__ w3, short* __restrict__ t13)
{
  __shared__ int As[BT][LDST];
  __shared__ int B1[BK][LDST];
  __shared__ int B3[BK][LDST];
  const int tx = threadIdx.x, ty = threadIdx.y;
  const int tid = ty * 16 + tx;
  const int col0 = blockIdx.x * BN;
  const int row0 = blockIdx.y * BT;
  const int lr = tid >> 4;
  const int lk = (tid & 15) << 2;
  int acc1[16] = {0};
  int acc3[16] = {0};
  for (int k0 = 0; k0 < DIMK; k0 += BK) {
    #pragma unroll
    for (int m = 0; m < 4; ++m) {
      const int r = lr + m * 16;
      *reinterpret_cast<int4*>(&As[r][lk]) =
          *reinterpret_cast<const int4*>(&x[(size_t)(row0 + r) * DIMK + k0 + lk]);
      const float4 f1 = *reinterpret_cast<const float4*>(&w1[(size_t)(col0 + r) * DIMK + k0 + lk]);
      const float4 f3 = *reinterpret_cast<const float4*>(&w3[(size_t)(col0 + r) * DIMK + k0 + lk]);
      B1[lk + 0][r] = __float2int_rn(f1.x * 65536.0f);
      B1[lk + 1][r] = __float2int_rn(f1.y * 65536.0f);
      B1[lk + 2][r] = __float2int_rn(f1.z * 65536.0f);
      B1[lk + 3][r] = __float2int_rn(f1.w * 65536.0f);
      B3[lk + 0][r] = __float2int_rn(f3.x * 65536.0f);
      B3[lk + 1][r] = __float2int_rn(f3.y * 65536.0f);
      B3[lk + 2][r] = __float2int_rn(f3.z * 65536.0f);
      B3[lk + 3][r] = __float2int_rn(f3.w * 65536.0f);
    }
    __syncthreads();
    #pragma unroll 8
    for (int kk = 0; kk < BK; ++kk) {
      const int4 b1 = *reinterpret_cast<const int4*>(&B1[kk][tx << 2]);
      const int4 b3 = *reinterpret_cast<const int4*>(&B3[kk][tx << 2]);
      #pragma unroll
      for (int i = 0; i < 4; ++i) {
        const int av = As[(ty << 2) + i][kk] & 255;
        acc1[i*4+0] = mad24(av, b1.x, acc1[i*4+0]);
        acc1[i*4+1] = mad24(av, b1.y, acc1[i*4+1]);
        acc1[i*4+2] = mad24(av, b1.z, acc1[i*4+2]);
        acc1[i*4+3] = mad24(av, b1.w, acc1[i*4+3]);
        acc3[i*4+0] = mad24(av, b3.x, acc3[i*4+0]);
        acc3[i*4+1] = mad24(av, b3.y, acc3[i*4+1]);
        acc3[i*4+2] = mad24(av, b3.z, acc3[i*4+2]);
        acc3[i*4+3] = mad24(av, b3.w, acc3[i*4+3]);
      }
    }
    __syncthreads();
  }
  #pragma unroll
  for (int i = 0; i < 4; ++i) {
    #pragma unroll
    for (int j = 0; j < 4; ++j) {
      const int g    = (acc1[i*4+j] + 32768) >> 16;
      const int q3   = (acc3[i*4+j] + 32768) >> 16;
      const int gate = gate_requant(g);
      const int tv = (int)(((ll)gate * (ll)q3 + 32768) >> 16);
      t13[(size_t)(row0 + (ty<<2) + i) * HID + col0 + (tx<<2) + j] = (short)tv;
    }
  }
}

__global__ __launch_bounds__(256)
void ffn_down_f(const short* __restrict__ t13, const float* __restrict__ w2,
                int* __restrict__ out)
{
  __shared__ int As[BT][LDST];
  __shared__ int Bs[BK][LDST];
  const int tx = threadIdx.x, ty = threadIdx.y;
  const int tid = ty * 16 + tx;
  const int col0 = blockIdx.x * BN;
  const int row0 = blockIdx.y * BT;
  const int lr = tid >> 4;
  const int lk = (tid & 15) << 2;
  const int ar = tid >> 3;
  const int ak = (tid & 7) << 3;
  int acc[16] = {0};
  for (int k0 = 0; k0 < HID; k0 += BK) {
    #pragma unroll
    for (int m = 0; m < 2; ++m) {
      const int r = ar + m * 32;
      const int4 v = *reinterpret_cast<const int4*>(&t13[(size_t)(row0 + r) * HID + k0 + ak]);
      As[r][ak+0] = (v.x << 16) >> 16;  As[r][ak+1] = v.x >> 16;
      As[r][ak+2] = (v.y << 16) >> 16;  As[r][ak+3] = v.y >> 16;
      As[r][ak+4] = (v.z << 16) >> 16;  As[r][ak+5] = v.z >> 16;
      As[r][ak+6] = (v.w << 16) >> 16;  As[r][ak+7] = v.w >> 16;
    }
    #pragma unroll
    for (int m = 0; m < 4; ++m) {
      const int r = lr + m * 16;
      const float4 f = *reinterpret_cast<const float4*>(&w2[(size_t)(col0 + r) * HID + k0 + lk]);
      Bs[lk + 0][r] = __float2int_rn(f.x * 65536.0f);
      Bs[lk + 1][r] = __float2int_rn(f.y * 65536.0f);
      Bs[lk + 2][r] = __float2int_rn(f.z * 65536.0f);
      Bs[lk + 3][r] = __float2int_rn(f.w * 65536.0f);
    }
    __syncthreads();
    #pragma unroll 8
    for (int kk = 0; kk < BK; ++kk) {
      const int4 b = *reinterpret_cast<const int4*>(&Bs[kk][tx << 2]);
      #pragma unroll
      for (int i = 0; i < 4; ++i) {
        const int av = As[(ty << 2) + i][kk];
        acc[i*4+0] = mad24(av, b.x, acc[i*4+0]);
        acc[i*4+1] = mad24(av, b.y, acc[i*4+1]);
        acc[i*4+2] = mad24(av, b.z, acc[i*4+2]);
        acc[i*4+3] = mad24(av, b.w, acc[i*4+3]);
      }
    }
    __syncthreads();
  }
  #pragma unroll
  for (int i = 0; i < 4; ++i) {
    #pragma unroll
    for (int j = 0; j < 4; ++j) {
      out[(size_t)(row0 + (ty<<2) + i) * DIMK + col0 + (tx<<2) + j] =
          (acc[i*4+j] + 32768) >> 16;
    }
  }
}

// ============================================================
extern "C" void kernel_launch(void* const* d_in, const int* in_sizes, int n_in,
                              void* d_out, int out_size, void* d_ws, size_t ws_size,
                              hipStream_t stream) {
  (void)in_sizes; (void)n_in; (void)out_size;
  const int*   x  = (const int*)d_in[0];
  const float* w1 = (const float*)d_in[1];
  const float* w2 = (const float*)d_in[2];
  const float* w3 = (const float*)d_in[3];
  int* out = (int*)d_out;
  char* ws = (char*)d_ws;

  if (ws_size >= WS_NEED) {
    char* t13 = ws + T13_OFF;
    int*  lut = (int*)(ws + LUT_OFF);
    int*  cs1 = (int*)(ws + CS1_OFF);
    int*  cs3 = (int*)(ws + CS3_OFF);
    char* xq  = ws + XQ_OFF;
    char* wq  = ws + WQ_OFF;

    hipMemsetAsync(ws + CS1_OFF, 0, 88064, stream);
    hipLaunchKernelGGL(lut_kernel, dim3(32), dim3(256), 0, stream, lut);
    hipLaunchKernelGGL(xq_kernel, dim3(1024), dim3(256), 0, stream, x, xq);
    hipLaunchKernelGGL(prequant_all, dim3(33024), dim3(256), 0, stream,
                       w1, w3, w2, wq, cs1, cs3);
    hipLaunchKernelGGL(up_gemm, dim3(TOK / 128, HID / 64), dim3(512), 0, stream,
                       xq, wq, cs1, cs3, lut, t13);
    hipLaunchKernelGGL(down_gemm, dim3(TOK / 128, DIMK / 64), dim3(512), 0, stream,
                       t13, wq + 4 * PLANE, wq + 5 * PLANE, out);
  } else {
    if (ws_size < (size_t)TOK * HID * sizeof(short)) return;
    short* t13 = (short*)ws;
    dim3 blk(16, 16);
    hipLaunchKernelGGL(ffn_up_f,   dim3(HID / BN, TOK / BT), blk, 0, stream, x, w1, w3, t13);
    hipLaunchKernelGGL(ffn_down_f, dim3(DIMK / BN, TOK / BT), blk, 0, stream, t13, w2, out);
  }
}

// Round 5
// 646.816 us; speedup vs baseline: 9.5634x; 1.0275x over previous
//
#include <hip/hip_runtime.h>
#include <hip/hip_fp16.h>
#include <math.h>

#define TOK  1024
#define DIMK 4096
#define HID  11008

typedef long long ll;
typedef int v4i  __attribute__((ext_vector_type(4)));
typedef int v16i __attribute__((ext_vector_type(16)));

// ---------- ws layout ----------
#define T13_OFF 0ull
#define LUT_OFF 11272192ull
#define CS1_OFF (LUT_OFF + 32768ull)
#define CS3_OFF (CS1_OFF + 44032ull)
#define XQ_OFF  (CS3_OFF + 44032ull)
#define WQ_OFF  (XQ_OFF + 4194304ull)
#define PLANE   45088768ull                          // 11008*4096 bytes
#define WS_NEED (WQ_OFF + 6ull * PLANE)              // ~273 MB

// ---------- exact fp16-silu requant (proven in round 2) ----------
__device__ __forceinline__ int gate_requant(int g) {
  const float vf = __half2float(__float2half((float)g * (1.0f / 65536.0f)));
  const float e32 = (float)exp(-(double)vf);
  const float e16 = __half2float(__float2half(e32));
  const float d16 = __half2float(__float2half(1.0f + e16));
  const float s16 = __half2float(__float2half(1.0f / d16));
  const float p16 = __half2float(__float2half(vf * s16));
  return __float2int_rn(p16 * 65536.0f);
}

__device__ __forceinline__ v16i vzero16() {
  v16i z;
  #pragma unroll
  for (int i = 0; i < 16; ++i) z[i] = 0;
  return z;
}

// async global->LDS, 16B per lane; lds ptr must be wave-uniform
__device__ __forceinline__ void gll(const void* g, void* l) {
  __builtin_amdgcn_global_load_lds((const __attribute__((address_space(1))) unsigned int*)g,
                                   (__attribute__((address_space(3))) unsigned int*)l,
                                   16, 0, 0);
}

// ============================================================
// Pre-pass kernels
// ============================================================

__global__ void lut_kernel(int* __restrict__ lut) {
  const int i = blockIdx.x * blockDim.x + threadIdx.x;   // 0..8191
  lut[i] = gate_requant(i - 4096);
}

// xq = (i8)(x - 128), packed bytes
__global__ __launch_bounds__(256)
void xq_kernel(const int* __restrict__ x, char* __restrict__ xq) {
  const size_t base = ((size_t)blockIdx.x * 256 + threadIdx.x) * 16;
  int w[4];
  #pragma unroll
  for (int i = 0; i < 4; ++i) {
    const int4 v = *reinterpret_cast<const int4*>(&x[base + i * 4]);
    w[i] = ((v.x & 255) | ((v.y & 255) << 8) | ((v.z & 255) << 16) | ((v.w & 255) << 24)) ^ 0x80808080;
  }
  *reinterpret_cast<int4*>(&xq[base]) = make_int4(w[0], w[1], w[2], w[3]);
}

// All three weight matrices in one dispatch; fully coalesced.
__global__ __launch_bounds__(256)
void prequant_all(const float* __restrict__ w1, const float* __restrict__ w3,
                  const float* __restrict__ w2, char* __restrict__ wq,
                  int* __restrict__ cs1, int* __restrict__ cs3)
{
  const int bid = blockIdx.x;
  const int m = bid / 11008;            // 0,1,2 (uniform per block)
  const int rb = bid - m * 11008;
  const float* src = (m == 0) ? w1 : ((m == 1) ? w3 : w2);
  int* lo = (int*)(wq + (size_t)(2 * m) * PLANE);
  int* hi = (int*)(wq + (size_t)(2 * m + 1) * PLANE);
  const size_t f4base = (size_t)rb * 1024;

  int sum = 0;
  #pragma unroll
  for (int j = 0; j < 4; ++j) {
    const size_t f4 = f4base + threadIdx.x + j * 256;
    const float4 f = *reinterpret_cast<const float4*>(&src[f4 * 4]);
    const int q0 = __float2int_rn(f.x * 65536.0f);
    const int q1 = __float2int_rn(f.y * 65536.0f);
    const int q2 = __float2int_rn(f.z * 65536.0f);
    const int q3 = __float2int_rn(f.w * 65536.0f);
    sum += q0 + q1 + q2 + q3;
    lo[f4] = (q0 & 127) | ((q1 & 127) << 8) | ((q2 & 127) << 16) | ((q3 & 127) << 24);
    hi[f4] = ((q0 >> 7) & 255) | (((q1 >> 7) & 255) << 8) |
             (((q2 >> 7) & 255) << 16) | (((q3 >> 7) & 255) << 24);
  }
  if (m < 2) {
    #pragma unroll
    for (int off = 32; off > 0; off >>= 1) sum += __shfl_xor(sum, off, 64);
    if ((threadIdx.x & 63) == 0) atomicAdd(((m == 0) ? cs1 : cs3) + rb, sum);
  }
}

// ============================================================
// Up GEMM, m=2: BT=128 rows, BN=64 cols, BK=64; 256 thr = 4 waves.
// Wave (rf2=w&1, cf=w>>1) computes 64 rows x 32 cols x 4 planes:
// per ks reads 2 A + 4 B frags -> 8 MFMAs (0.75 KB LDS / MFMA).
// LDS/tile: A = 8 segs (4 rc x 2 ks), B = 16 segs (4 planes x 2 ks x 2 cf).
// Triple buffer, counted vmcnt (6 gll/wave/tile). XCD-swizzled grid.
// ============================================================
#define UP_BUF 24576

__global__ __launch_bounds__(256, 2)
void up_gemm(const char* __restrict__ xq, const char* __restrict__ wq,
             const int* __restrict__ csum1, const int* __restrict__ csum3,
             const int* __restrict__ lut, char* __restrict__ t13)
{
  __shared__ char smem[3 * UP_BUF];
  const int tid = threadIdx.x;
  const int w = tid >> 6, l = tid & 63;
  const int rf2 = w & 1, cf = w >> 1;
  const int l16 = l * 16;

  // bijective XCD swizzle: 1376 = 8 * 172; same-col token-blocks adjacent per XCD
  const int flat = blockIdx.x;
  const int g = (flat & 7) * 172 + (flat >> 3);
  const int col0 = (g >> 3) * 64;
  const int row0 = (g & 7) * 128;

  // staging (wave w): A rows rc=w (2 ks segs) + B plane p=w (4 ks/cf segs)
  const char* gA = xq + (size_t)(row0 + w * 32 + (l & 31)) * DIMK + (l >> 5) * 16;
  const char* gBp = wq + (size_t)w * PLANE + (l >> 5) * 16;
  const char* gB0 = gBp + (size_t)(col0 +  0 + (l & 31)) * DIMK +  0;  // ks0 cf0
  const char* gB1 = gBp + (size_t)(col0 + 32 + (l & 31)) * DIMK +  0;  // ks0 cf1
  const char* gB2 = gBp + (size_t)(col0 +  0 + (l & 31)) * DIMK + 32;  // ks1 cf0
  const char* gB3 = gBp + (size_t)(col0 + 32 + (l & 31)) * DIMK + 32;  // ks1 cf1
  const unsigned dA0 = (w * 2 + 0) * 1024, dA1 = (w * 2 + 1) * 1024;
  const unsigned dB0 = 8192 + (w * 4 + 0) * 1024;   // sb = w*4 + (ks*2+cf)
  const unsigned dB1 = 8192 + (w * 4 + 1) * 1024;
  const unsigned dB2 = 8192 + (w * 4 + 2) * 1024;
  const unsigned dB3 = 8192 + (w * 4 + 3) * 1024;

  v16i s0p0 = vzero16(), s0p1 = vzero16(), s0p2 = vzero16(), s0p3 = vzero16();
  v16i s1p0 = vzero16(), s1p1 = vzero16(), s1p2 = vzero16(), s1p3 = vzero16();

  #define UP_STAGE(kb, bo) { \
    gll(gA + (kb), smem + (bo) + dA0);  gll(gA + (kb) + 32, smem + (bo) + dA1); \
    gll(gB0 + (kb), smem + (bo) + dB0); gll(gB1 + (kb), smem + (bo) + dB1); \
    gll(gB2 + (kb), smem + (bo) + dB2); gll(gB3 + (kb), smem + (bo) + dB3); }

  // prologue: tiles 0 and 1
  UP_STAGE(0, 0);
  UP_STAGE(64, UP_BUF);

  const int NT = DIMK / 64;
  unsigned co = 0, so = 2 * UP_BUF;
  for (int kt = 0; kt < NT; ++kt) {
    if (kt + 2 < NT) {
      UP_STAGE((kt + 2) * 64, so);
      so = (so == 2 * UP_BUF) ? 0 : so + UP_BUF;
      asm volatile("s_waitcnt vmcnt(12)" ::: "memory");
    } else if (kt + 1 < NT) {
      asm volatile("s_waitcnt vmcnt(6)" ::: "memory");
    } else {
      asm volatile("s_waitcnt vmcnt(0)" ::: "memory");
    }
    __builtin_amdgcn_s_barrier();
    const char* sb = smem + co;
    __builtin_amdgcn_s_setprio(1);
    #pragma unroll
    for (int ks = 0; ks < 2; ++ks) {
      const v4i av0 = *(const v4i*)(sb + ((rf2 * 2 + 0) * 2 + ks) * 1024 + l16);
      const v4i av1 = *(const v4i*)(sb + ((rf2 * 2 + 1) * 2 + ks) * 1024 + l16);
      const v4i b0 = *(const v4i*)(sb + 8192 + (0 * 4 + ks * 2 + cf) * 1024 + l16);
      const v4i b1 = *(const v4i*)(sb + 8192 + (1 * 4 + ks * 2 + cf) * 1024 + l16);
      const v4i b2 = *(const v4i*)(sb + 8192 + (2 * 4 + ks * 2 + cf) * 1024 + l16);
      const v4i b3 = *(const v4i*)(sb + 8192 + (3 * 4 + ks * 2 + cf) * 1024 + l16);
      s0p0 = __builtin_amdgcn_mfma_i32_32x32x32_i8(av0, b0, s0p0, 0, 0, 0);
      s0p1 = __builtin_amdgcn_mfma_i32_32x32x32_i8(av0, b1, s0p1, 0, 0, 0);
      s0p2 = __builtin_amdgcn_mfma_i32_32x32x32_i8(av0, b2, s0p2, 0, 0, 0);
      s0p3 = __builtin_amdgcn_mfma_i32_32x32x32_i8(av0, b3, s0p3, 0, 0, 0);
      s1p0 = __builtin_amdgcn_mfma_i32_32x32x32_i8(av1, b0, s1p0, 0, 0, 0);
      s1p1 = __builtin_amdgcn_mfma_i32_32x32x32_i8(av1, b1, s1p1, 0, 0, 0);
      s1p2 = __builtin_amdgcn_mfma_i32_32x32x32_i8(av1, b2, s1p2, 0, 0, 0);
      s1p3 = __builtin_amdgcn_mfma_i32_32x32x32_i8(av1, b3, s1p3, 0, 0, 0);
    }
    __builtin_amdgcn_s_setprio(0);
    __builtin_amdgcn_s_barrier();
    co = (co == 2 * UP_BUF) ? 0 : co + UP_BUF;
  }
  #undef UP_STAGE

  const int col = col0 + cf * 32 + (l & 31);
  const int cs1 = csum1[col], cs3 = csum3[col];
  #define UP_EPI(A0, A1, A2, A3, sub) { \
    _Pragma("unroll") \
    for (int r = 0; r < 16; ++r) { \
      const int row = row0 + rf2 * 64 + (sub) * 32 + (r & 3) + 8 * (r >> 2) + 4 * (l >> 5); \
      const ll t1 = (ll)A0[r] + (((ll)A1[r] + cs1) << 7); \
      int gg = (int)((t1 + 32768) >> 16); \
      gg = gg < -4096 ? -4096 : (gg > 4095 ? 4095 : gg); \
      const ll t3 = (ll)A2[r] + (((ll)A3[r] + cs3) << 7); \
      const int q3 = (int)((t3 + 32768) >> 16); \
      const int gate = lut[gg + 4096]; \
      t13[(size_t)row * HID + col] = (char)((int)(((ll)gate * q3 + 32768) >> 16)); \
    } }
  UP_EPI(s0p0, s0p1, s0p2, s0p3, 0)
  UP_EPI(s1p0, s1p1, s1p2, s1p3, 1)
  #undef UP_EPI
}

// ============================================================
// Down GEMM, m=2: BT=128, BN=64, BK=64 over HID; 256 thr = 4 waves.
// A = 8 segs, B = 8 segs (2 planes x 2 ks x 2 cf). 16KB/buffer, triple.
// ============================================================
#define DN_BUF 16384

__global__ __launch_bounds__(256, 2)
void down_gemm(const char* __restrict__ t13, const char* __restrict__ w2lo,
               const char* __restrict__ w2hi, int* __restrict__ out)
{
  __shared__ char smem[3 * DN_BUF];
  const int tid = threadIdx.x;
  const int w = tid >> 6, l = tid & 63;
  const int rf2 = w & 1, cf = w >> 1;
  const int l16 = l * 16;

  // bijective XCD swizzle: 512 = 8 * 64
  const int flat = blockIdx.x;
  const int g = (flat & 7) * 64 + (flat >> 3);
  const int col0 = (g >> 3) * 64;
  const int row0 = (g & 7) * 128;

  // staging (wave w): A rc=w (2 segs) + B sbs {2w, 2w+1}: p=w>>1, ks=w&1, cf=j
  const char* gA = t13 + (size_t)(row0 + w * 32 + (l & 31)) * HID + (l >> 5) * 16;
  const char* pB = (w >> 1) ? w2hi : w2lo;
  const char* gB0 = pB + (size_t)(col0 +  0 + (l & 31)) * HID + (w & 1) * 32 + (l >> 5) * 16;
  const char* gB1 = pB + (size_t)(col0 + 32 + (l & 31)) * HID + (w & 1) * 32 + (l >> 5) * 16;
  const unsigned dA0 = (w * 2 + 0) * 1024, dA1 = (w * 2 + 1) * 1024;
  const unsigned dB0 = 8192 + (2 * w + 0) * 1024;
  const unsigned dB1 = 8192 + (2 * w + 1) * 1024;

  v16i d0L = vzero16(), d0H = vzero16(), d1L = vzero16(), d1H = vzero16();

  #define DN_STAGE(kb, bo) { \
    gll(gA + (kb), smem + (bo) + dA0);  gll(gA + (kb) + 32, smem + (bo) + dA1); \
    gll(gB0 + (kb), smem + (bo) + dB0); gll(gB1 + (kb), smem + (bo) + dB1); }

  DN_STAGE(0, 0);
  DN_STAGE(64, DN_BUF);

  const int NT = HID / 64;
  unsigned co = 0, so = 2 * DN_BUF;
  for (int kt = 0; kt < NT; ++kt) {
    if (kt + 2 < NT) {
      DN_STAGE((kt + 2) * 64, so);
      so = (so == 2 * DN_BUF) ? 0 : so + DN_BUF;
      asm volatile("s_waitcnt vmcnt(8)" ::: "memory");
    } else if (kt + 1 < NT) {
      asm volatile("s_waitcnt vmcnt(4)" ::: "memory");
    } else {
      asm volatile("s_waitcnt vmcnt(0)" ::: "memory");
    }
    __builtin_amdgcn_s_barrier();
    const char* sb = smem + co;
    __builtin_amdgcn_s_setprio(1);
    #pragma unroll
    for (int ks = 0; ks < 2; ++ks) {
      const v4i av0 = *(const v4i*)(sb + ((rf2 * 2 + 0) * 2 + ks) * 1024 + l16);
      const v4i av1 = *(const v4i*)(sb + ((rf2 * 2 + 1) * 2 + ks) * 1024 + l16);
      const v4i bL = *(const v4i*)(sb + 8192 + (0 * 4 + ks * 2 + cf) * 1024 + l16);
      const v4i bH = *(const v4i*)(sb + 8192 + (1 * 4 + ks * 2 + cf) * 1024 + l16);
      d0L = __builtin_amdgcn_mfma_i32_32x32x32_i8(av0, bL, d0L, 0, 0, 0);
      d0H = __builtin_amdgcn_mfma_i32_32x32x32_i8(av0, bH, d0H, 0, 0, 0);
      d1L = __builtin_amdgcn_mfma_i32_32x32x32_i8(av1, bL, d1L, 0, 0, 0);
      d1H = __builtin_amdgcn_mfma_i32_32x32x32_i8(av1, bH, d1H, 0, 0, 0);
    }
    __builtin_amdgcn_s_setprio(0);
    __builtin_amdgcn_s_barrier();
    co = (co == 2 * DN_BUF) ? 0 : co + DN_BUF;
  }
  #undef DN_STAGE

  const int col = col0 + cf * 32 + (l & 31);
  #pragma unroll
  for (int r = 0; r < 16; ++r) {
    const int row = row0 + rf2 * 64 + (r & 3) + 8 * (r >> 2) + 4 * (l >> 5);
    out[(size_t)row * DIMK + col] = (int)((((ll)d0L[r] + ((ll)d0H[r] << 7)) + 32768) >> 16);
  }
  #pragma unroll
  for (int r = 0; r < 16; ++r) {
    const int row = row0 + rf2 * 64 + 32 + (r & 3) + 8 * (r >> 2) + 4 * (l >> 5);
    out[(size_t)row * DIMK + col] = (int)((((ll)d1L[r] + ((ll)d1H[r] << 7)) + 32768) >> 16);
  }
}

// ============================================================
// Fallback (round-2 passing VALU kernels, used if ws too small)
// ============================================================
#define BT 64
#define BN 64
#define BK 64
#define LDST 68

__device__ __forceinline__ int mad24(int a, int b, int c) {
  return ((a << 8) >> 8) * ((b << 8) >> 8) + c;
}

__global__ __launch_bounds__(256)
void ffn_up_f(const int* __restrict__ x, const float* __restrict__ w1,
              const float* __restrict__ w3, short* __restrict__ t13)
{
  __shared__ int As[BT][LDST];
  __shared__ int B1[BK][LDST];
  __shared__ int B3[BK][LDST];
  const int tx = threadIdx.x, ty = threadIdx.y;
  const int tid = ty * 16 + tx;
  const int col0 = blockIdx.x * BN;
  const int row0 = blockIdx.y * BT;
  const int lr = tid >> 4;
  const int lk = (tid & 15) << 2;
  int acc1[16] = {0};
  int acc3[16] = {0};
  for (int k0 = 0; k0 < DIMK; k0 += BK) {
    #pragma unroll
    for (int m = 0; m < 4; ++m) {
      const int r = lr + m * 16;
      *reinterpret_cast<int4*>(&As[r][lk]) =
          *reinterpret_cast<const int4*>(&x[(size_t)(row0 + r) * DIMK + k0 + lk]);
      const float4 f1 = *reinterpret_cast<const float4*>(&w1[(size_t)(col0 + r) * DIMK + k0 + lk]);
      const float4 f3 = *reinterpret_cast<const float4*>(&w3[(size_t)(col0 + r) * DIMK + k0 + lk]);
      B1[lk + 0][r] = __float2int_rn(f1.x * 65536.0f);
      B1[lk + 1][r] = __float2int_rn(f1.y * 65536.0f);
      B1[lk + 2][r] = __float2int_rn(f1.z * 65536.0f);
      B1[lk + 3][r] = __float2int_rn(f1.w * 65536.0f);
      B3[lk + 0][r] = __float2int_rn(f3.x * 65536.0f);
      B3[lk + 1][r] = __float2int_rn(f3.y * 65536.0f);
      B3[lk + 2][r] = __float2int_rn(f3.z * 65536.0f);
      B3[lk + 3][r] = __float2int_rn(f3.w * 65536.0f);
    }
    __syncthreads();
    #pragma unroll 8
    for (int kk = 0; kk < BK; ++kk) {
      const int4 b1 = *reinterpret_cast<const int4*>(&B1[kk][tx << 2]);
      const int4 b3 = *reinterpret_cast<const int4*>(&B3[kk][tx << 2]);
      #pragma unroll
      for (int i = 0; i < 4; ++i) {
        const int av = As[(ty << 2) + i][kk] & 255;
        acc1[i*4+0] = mad24(av, b1.x, acc1[i*4+0]);
        acc1[i*4+1] = mad24(av, b1.y, acc1[i*4+1]);
        acc1[i*4+2] = mad24(av, b1.z, acc1[i*4+2]);
        acc1[i*4+3] = mad24(av, b1.w, acc1[i*4+3]);
        acc3[i*4+0] = mad24(av, b3.x, acc3[i*4+0]);
        acc3[i*4+1] = mad24(av, b3.y, acc3[i*4+1]);
        acc3[i*4+2] = mad24(av, b3.z, acc3[i*4+2]);
        acc3[i*4+3] = mad24(av, b3.w, acc3[i*4+3]);
      }
    }
    __syncthreads();
  }
  #pragma unroll
  for (int i = 0; i < 4; ++i) {
    #pragma unroll
    for (int j = 0; j < 4; ++j) {
      const int g    = (acc1[i*4+j] + 32768) >> 16;
      const int q3   = (acc3[i*4+j] + 32768) >> 16;
      const int gate = gate_requant(g);
      const int tv = (int)(((ll)gate * (ll)q3 + 32768) >> 16);
      t13[(size_t)(row0 + (ty<<2) + i) * HID + col0 + (tx<<2) + j] = (short)tv;
    }
  }
}

__global__ __launch_bounds__(256)
void ffn_down_f(const short* __restrict__ t13, const float* __restrict__ w2,
                int* __restrict__ out)
{
  __shared__ int As[BT][LDST];
  __shared__ int Bs[BK][LDST];
  const int tx = threadIdx.x, ty = threadIdx.y;
  const int tid = ty * 16 + tx;
  const int col0 = blockIdx.x * BN;
  const int row0 = blockIdx.y * BT;
  const int lr = tid >> 4;
  const int lk = (tid & 15) << 2;
  const int ar = tid >> 3;
  const int ak = (tid & 7) << 3;
  int acc[16] = {0};
  for (int k0 = 0; k0 < HID; k0 += BK) {
    #pragma unroll
    for (int m = 0; m < 2; ++m) {
      const int r = ar + m * 32;
      const int4 v = *reinterpret_cast<const int4*>(&t13[(size_t)(row0 + r) * HID + k0 + ak]);
      As[r][ak+0] = (v.x << 16) >> 16;  As[r][ak+1] = v.x >> 16;
      As[r][ak+2] = (v.y << 16) >> 16;  As[r][ak+3] = v.y >> 16;
      As[r][ak+4] = (v.z << 16) >> 16;  As[r][ak+5] = v.z >> 16;
      As[r][ak+6] = (v.w << 16) >> 16;  As[r][ak+7] = v.w >> 16;
    }
    #pragma unroll
    for (int m = 0; m < 4; ++m) {
      const int r = lr + m * 16;
      const float4 f = *reinterpret_cast<const float4*>(&w2[(size_t)(col0 + r) * HID + k0 + lk]);
      Bs[lk + 0][r] = __float2int_rn(f.x * 65536.0f);
      Bs[lk + 1][r] = __float2int_rn(f.y * 65536.0f);
      Bs[lk + 2][r] = __float2int_rn(f.z * 65536.0f);
      Bs[lk + 3][r] = __float2int_rn(f.w * 65536.0f);
    }
    __syncthreads();
    #pragma unroll 8
    for (int kk = 0; kk < BK; ++kk) {
      const int4 b = *reinterpret_cast<const int4*>(&Bs[kk][tx << 2]);
      #pragma unroll
      for (int i = 0; i < 4; ++i) {
        const int av = As[(ty << 2) + i][kk];
        acc[i*4+0] = mad24(av, b.x, acc[i*4+0]);
        acc[i*4+1] = mad24(av, b.y, acc[i*4+1]);
        acc[i*4+2] = mad24(av, b.z, acc[i*4+2]);
        acc[i*4+3] = mad24(av, b.w, acc[i*4+3]);
      }
    }
    __syncthreads();
  }
  #pragma unroll
  for (int i = 0; i < 4; ++i) {
    #pragma unroll
    for (int j = 0; j < 4; ++j) {
      out[(size_t)(row0 + (ty<<2) + i) * DIMK + col0 + (tx<<2) + j] =
          (acc[i*4+j] + 32768) >> 16;
    }
  }
}

// ============================================================
extern "C" void kernel_launch(void* const* d_in, const int* in_sizes, int n_in,
                              void* d_out, int out_size, void* d_ws, size_t ws_size,
                              hipStream_t stream) {
  (void)in_sizes; (void)n_in; (void)out_size;
  const int*   x  = (const int*)d_in[0];
  const float* w1 = (const float*)d_in[1];
  const float* w2 = (const float*)d_in[2];
  const float* w3 = (const float*)d_in[3];
  int* out = (int*)d_out;
  char* ws = (char*)d_ws;

  if (ws_size >= WS_NEED) {
    char* t13 = ws + T13_OFF;
    int*  lut = (int*)(ws + LUT_OFF);
    int*  cs1 = (int*)(ws + CS1_OFF);
    int*  cs3 = (int*)(ws + CS3_OFF);
    char* xq  = ws + XQ_OFF;
    char* wq  = ws + WQ_OFF;

    hipMemsetAsync(ws + CS1_OFF, 0, 88064, stream);
    hipLaunchKernelGGL(lut_kernel, dim3(32), dim3(256), 0, stream, lut);
    hipLaunchKernelGGL(xq_kernel, dim3(1024), dim3(256), 0, stream, x, xq);
    hipLaunchKernelGGL(prequant_all, dim3(33024), dim3(256), 0, stream,
                       w1, w3, w2, wq, cs1, cs3);
    hipLaunchKernelGGL(up_gemm, dim3(1376), dim3(256), 0, stream,
                       xq, wq, cs1, cs3, lut, t13);
    hipLaunchKernelGGL(down_gemm, dim3(512), dim3(256), 0, stream,
                       t13, wq + 4 * PLANE, wq + 5 * PLANE, out);
  } else {
    if (ws_size < (size_t)TOK * HID * sizeof(short)) return;
    short* t13 = (short*)ws;
    dim3 blk(16, 16);
    hipLaunchKernelGGL(ffn_up_f,   dim3(HID / BN, TOK / BT), blk, 0, stream, x, w1, w3, t13);
    hipLaunchKernelGGL(ffn_down_f, dim3(DIMK / BN, TOK / BT), blk, 0, stream, t13, w2, out);
  }
}

// Round 6
// 578.082 us; speedup vs baseline: 10.7005x; 1.1189x over previous
//
#include <hip/hip_runtime.h>
#include <hip/hip_fp16.h>
#include <math.h>

#define TOK  1024
#define DIMK 4096
#define HID  11008

typedef long long ll;
typedef int v4i  __attribute__((ext_vector_type(4)));
typedef int v16i __attribute__((ext_vector_type(16)));

// ---------- ws layout ----------
#define T13_OFF 0ull
#define LUT_OFF 11272192ull
#define CS1_OFF (LUT_OFF + 32768ull)
#define CS3_OFF (CS1_OFF + 44032ull)
#define XQ_OFF  (CS3_OFF + 44032ull)
#define WQ_OFF  (XQ_OFF + 4194304ull)
#define PLANE   45088768ull                          // 11008*4096 bytes
#define WS_NEED (WQ_OFF + 6ull * PLANE)              // ~273 MB

// ---------- exact fp16-silu requant (proven in round 2) ----------
__device__ __forceinline__ int gate_requant(int g) {
  const float vf = __half2float(__float2half((float)g * (1.0f / 65536.0f)));
  const float e32 = (float)exp(-(double)vf);
  const float e16 = __half2float(__float2half(e32));
  const float d16 = __half2float(__float2half(1.0f + e16));
  const float s16 = __half2float(__float2half(1.0f / d16));
  const float p16 = __half2float(__float2half(vf * s16));
  return __float2int_rn(p16 * 65536.0f);
}

__device__ __forceinline__ v16i vzero16() {
  v16i z;
  #pragma unroll
  for (int i = 0; i < 16; ++i) z[i] = 0;
  return z;
}

// async global->LDS, 16B per lane; lds ptr must be wave-uniform
__device__ __forceinline__ void gll(const void* g, void* l) {
  __builtin_amdgcn_global_load_lds((const __attribute__((address_space(1))) unsigned int*)g,
                                   (__attribute__((address_space(3))) unsigned int*)l,
                                   16, 0, 0);
}

// ============================================================
// Pre-pass kernels
// ============================================================

__global__ void lut_kernel(int* __restrict__ lut) {
  const int i = blockIdx.x * blockDim.x + threadIdx.x;   // 0..8191
  lut[i] = gate_requant(i - 4096);
}

// xq = (i8)(x - 128), packed bytes
__global__ __launch_bounds__(256)
void xq_kernel(const int* __restrict__ x, char* __restrict__ xq) {
  const size_t base = ((size_t)blockIdx.x * 256 + threadIdx.x) * 16;
  int w[4];
  #pragma unroll
  for (int i = 0; i < 4; ++i) {
    const int4 v = *reinterpret_cast<const int4*>(&x[base + i * 4]);
    w[i] = ((v.x & 255) | ((v.y & 255) << 8) | ((v.z & 255) << 16) | ((v.w & 255) << 24)) ^ 0x80808080;
  }
  *reinterpret_cast<int4*>(&xq[base]) = make_int4(w[0], w[1], w[2], w[3]);
}

// All three weight matrices in one dispatch; fully coalesced.
__global__ __launch_bounds__(256)
void prequant_all(const float* __restrict__ w1, const float* __restrict__ w3,
                  const float* __restrict__ w2, char* __restrict__ wq,
                  int* __restrict__ cs1, int* __restrict__ cs3)
{
  const int bid = blockIdx.x;
  const int m = bid / 11008;            // 0,1,2 (uniform per block)
  const int rb = bid - m * 11008;
  const float* src = (m == 0) ? w1 : ((m == 1) ? w3 : w2);
  int* lo = (int*)(wq + (size_t)(2 * m) * PLANE);
  int* hi = (int*)(wq + (size_t)(2 * m + 1) * PLANE);
  const size_t f4base = (size_t)rb * 1024;

  int sum = 0;
  #pragma unroll
  for (int j = 0; j < 4; ++j) {
    const size_t f4 = f4base + threadIdx.x + j * 256;
    const float4 f = *reinterpret_cast<const float4*>(&src[f4 * 4]);
    const int q0 = __float2int_rn(f.x * 65536.0f);
    const int q1 = __float2int_rn(f.y * 65536.0f);
    const int q2 = __float2int_rn(f.z * 65536.0f);
    const int q3 = __float2int_rn(f.w * 65536.0f);
    sum += q0 + q1 + q2 + q3;
    lo[f4] = (q0 & 127) | ((q1 & 127) << 8) | ((q2 & 127) << 16) | ((q3 & 127) << 24);
    hi[f4] = ((q0 >> 7) & 255) | (((q1 >> 7) & 255) << 8) |
             (((q2 >> 7) & 255) << 16) | (((q3 >> 7) & 255) << 24);
  }
  if (m < 2) {
    #pragma unroll
    for (int off = 32; off > 0; off >>= 1) sum += __shfl_xor(sum, off, 64);
    if ((threadIdx.x & 63) == 0) atomicAdd(((m == 0) ? cs1 : cs3) + rb, sum);
  }
}

// ============================================================
// Up GEMM: BT=256 rows, BN=64 cols, 4 planes, BK=64; 512 thr = 8 waves.
// Wave (rf=w&3, cf=w>>2): rows rf*64..+64, cols cf*32..+32, all 4 planes.
// Per K-tile: 2 phases (ks); per phase 6 ds_read_b128 -> 8 MFMA (setprio),
// no mid barrier (waves skew -> LDS/matrix overlap). Triple buffer 3x32KB,
// counted vmcnt (4 gll/wave/tile, depth 2 -> vmcnt(8)). XCD swizzle 688=8*86.
// ============================================================
#define UP_BUF 32768

__global__ __launch_bounds__(512, 1)
void up_gemm(const char* __restrict__ xq, const char* __restrict__ wq,
             const int* __restrict__ csum1, const int* __restrict__ csum3,
             const int* __restrict__ lut, char* __restrict__ t13)
{
  __shared__ char smem[3 * UP_BUF];
  const int tid = threadIdx.x;
  const int w = tid >> 6, l = tid & 63;
  const int rf = w & 3, cf = w >> 2;
  const int l16 = l * 16;

  // bijective XCD swizzle: 688 = 8 * 86; per XCD: consecutive g share col0
  const int flat = blockIdx.x;
  const int g = (flat & 7) * 86 + (flat >> 3);
  const int col0 = (g >> 2) * 64;
  const int row0 = (g & 3) * 256;

  // staging (wave w): A segs {2w,2w+1} (rc=w, ks=0/1), B segs {2w,2w+1}
  // (plane=w>>1, cs=w&1, ks=0/1). seg = 1KB; A at 0..16K, B at 16K..32K.
  const char* gA = xq + (size_t)(row0 + w * 32 + (l & 31)) * DIMK + (l >> 5) * 16;
  const char* gB = wq + (size_t)(w >> 1) * PLANE
                 + (size_t)(col0 + (w & 1) * 32 + (l & 31)) * DIMK + (l >> 5) * 16;
  const unsigned dA0 = (2 * w + 0) * 1024, dA1 = (2 * w + 1) * 1024;
  const unsigned dB0 = 16384 + (2 * w + 0) * 1024, dB1 = 16384 + (2 * w + 1) * 1024;

  v16i acc[2][4];
  #pragma unroll
  for (int m = 0; m < 2; ++m)
    #pragma unroll
    for (int p = 0; p < 4; ++p) acc[m][p] = vzero16();

  #define UP_STAGE(kb, bo) { \
    gll(gA + (kb), smem + (bo) + dA0);      gll(gA + (kb) + 32, smem + (bo) + dA1); \
    gll(gB + (kb), smem + (bo) + dB0);      gll(gB + (kb) + 32, smem + (bo) + dB1); }

  #define UP_PHASE(ks) { \
    const v4i av0 = *(const v4i*)(sb + (rf * 4 + 0 + (ks)) * 1024 + l16); \
    const v4i av1 = *(const v4i*)(sb + (rf * 4 + 2 + (ks)) * 1024 + l16); \
    const v4i b0  = *(const v4i*)(sb + 16384 + (0 * 4 + cf * 2 + (ks)) * 1024 + l16); \
    const v4i b1  = *(const v4i*)(sb + 16384 + (1 * 4 + cf * 2 + (ks)) * 1024 + l16); \
    const v4i b2  = *(const v4i*)(sb + 16384 + (2 * 4 + cf * 2 + (ks)) * 1024 + l16); \
    const v4i b3  = *(const v4i*)(sb + 16384 + (3 * 4 + cf * 2 + (ks)) * 1024 + l16); \
    __builtin_amdgcn_s_setprio(1); \
    acc[0][0] = __builtin_amdgcn_mfma_i32_32x32x32_i8(av0, b0, acc[0][0], 0, 0, 0); \
    acc[0][1] = __builtin_amdgcn_mfma_i32_32x32x32_i8(av0, b1, acc[0][1], 0, 0, 0); \
    acc[0][2] = __builtin_amdgcn_mfma_i32_32x32x32_i8(av0, b2, acc[0][2], 0, 0, 0); \
    acc[0][3] = __builtin_amdgcn_mfma_i32_32x32x32_i8(av0, b3, acc[0][3], 0, 0, 0); \
    acc[1][0] = __builtin_amdgcn_mfma_i32_32x32x32_i8(av1, b0, acc[1][0], 0, 0, 0); \
    acc[1][1] = __builtin_amdgcn_mfma_i32_32x32x32_i8(av1, b1, acc[1][1], 0, 0, 0); \
    acc[1][2] = __builtin_amdgcn_mfma_i32_32x32x32_i8(av1, b2, acc[1][2], 0, 0, 0); \
    acc[1][3] = __builtin_amdgcn_mfma_i32_32x32x32_i8(av1, b3, acc[1][3], 0, 0, 0); \
    __builtin_amdgcn_s_setprio(0); }

  // prologue: stage tiles 0 and 1
  UP_STAGE(0, 0);
  UP_STAGE(64, UP_BUF);

  const int NT = DIMK / 64;
  unsigned co = 0, so = 2 * UP_BUF;
  for (int kt = 0; kt < NT; ++kt) {
    if (kt + 2 < NT) {
      UP_STAGE((kt + 2) * 64, so);
      so = (so == 2 * UP_BUF) ? 0 : so + UP_BUF;
      asm volatile("s_waitcnt vmcnt(8)" ::: "memory");   // tile kt landed
    } else if (kt + 1 < NT) {
      asm volatile("s_waitcnt vmcnt(4)" ::: "memory");
    } else {
      asm volatile("s_waitcnt vmcnt(0)" ::: "memory");
    }
    __builtin_amdgcn_s_barrier();       // all waves' tile-kt data visible
    const char* sb = smem + co;
    UP_PHASE(0)
    UP_PHASE(1)
    __builtin_amdgcn_s_barrier();       // reads of slot co done -> safe to overwrite
    co = (co == 2 * UP_BUF) ? 0 : co + UP_BUF;
  }
  #undef UP_STAGE
  #undef UP_PHASE

  const int col = col0 + cf * 32 + (l & 31);
  const int cs1v = csum1[col], cs3v = csum3[col];
  #pragma unroll
  for (int m = 0; m < 2; ++m) {
    #pragma unroll
    for (int r = 0; r < 16; ++r) {
      const int row = row0 + rf * 64 + m * 32 + (r & 3) + 8 * (r >> 2) + 4 * (l >> 5);
      const ll t1 = (ll)acc[m][0][r] + (((ll)acc[m][1][r] + cs1v) << 7);
      int gg = (int)((t1 + 32768) >> 16);
      gg = gg < -4096 ? -4096 : (gg > 4095 ? 4095 : gg);
      const ll t3 = (ll)acc[m][2][r] + (((ll)acc[m][3][r] + cs3v) << 7);
      const int q3 = (int)((t3 + 32768) >> 16);
      const int gate = lut[gg + 4096];
      t13[(size_t)row * HID + col] = (char)((int)(((ll)gate * q3 + 32768) >> 16));
    }
  }
}

// ============================================================
// Down GEMM: BT=256, BN=64, 2 planes, BK=64 over HID; 512 thr = 8 waves.
// Wave (rf=w&3, cf=w>>2): rows rf*64..+64, cols cf*32..+32, both planes.
// Grid exactly 256 blocks = 1/CU. Triple buffer 3x24KB, vmcnt(6) (3 gll/wave).
// ============================================================
#define DN_BUF 24576

__global__ __launch_bounds__(512, 1)
void down_gemm(const char* __restrict__ t13, const char* __restrict__ w2lo,
               const char* __restrict__ w2hi, int* __restrict__ out)
{
  __shared__ char smem[3 * DN_BUF];
  const int tid = threadIdx.x;
  const int w = tid >> 6, l = tid & 63;
  const int rf = w & 3, cf = w >> 2;
  const int l16 = l * 16;

  // bijective XCD swizzle: 256 = 8 * 32
  const int flat = blockIdx.x;
  const int g = (flat & 7) * 32 + (flat >> 3);
  const int col0 = (g >> 2) * 64;
  const int row0 = (g & 3) * 256;

  // staging (wave w): A segs {2w,2w+1} (rc=w, ks=0/1);
  // B seg w: plane=w>>2, cs=(w>>1)&1, ks=w&1.
  const char* gA = t13 + (size_t)(row0 + w * 32 + (l & 31)) * HID + (l >> 5) * 16;
  const char* pB = (w >> 2) ? w2hi : w2lo;
  const char* gB = pB + (size_t)(col0 + ((w >> 1) & 1) * 32 + (l & 31)) * HID
                 + (w & 1) * 32 + (l >> 5) * 16;
  const unsigned dA0 = (2 * w + 0) * 1024, dA1 = (2 * w + 1) * 1024;
  const unsigned dB = 16384 + w * 1024;

  v16i acc[2][2];
  #pragma unroll
  for (int m = 0; m < 2; ++m)
    #pragma unroll
    for (int p = 0; p < 2; ++p) acc[m][p] = vzero16();

  #define DN_STAGE(kb, bo) { \
    gll(gA + (kb), smem + (bo) + dA0);  gll(gA + (kb) + 32, smem + (bo) + dA1); \
    gll(gB + (kb), smem + (bo) + dB); }

  #define DN_PHASE(ks) { \
    const v4i av0 = *(const v4i*)(sb + (rf * 4 + 0 + (ks)) * 1024 + l16); \
    const v4i av1 = *(const v4i*)(sb + (rf * 4 + 2 + (ks)) * 1024 + l16); \
    const v4i bL  = *(const v4i*)(sb + 16384 + (0 * 4 + cf * 2 + (ks)) * 1024 + l16); \
    const v4i bH  = *(const v4i*)(sb + 16384 + (1 * 4 + cf * 2 + (ks)) * 1024 + l16); \
    __builtin_amdgcn_s_setprio(1); \
    acc[0][0] = __builtin_amdgcn_mfma_i32_32x32x32_i8(av0, bL, acc[0][0], 0, 0, 0); \
    acc[0][1] = __builtin_amdgcn_mfma_i32_32x32x32_i8(av0, bH, acc[0][1], 0, 0, 0); \
    acc[1][0] = __builtin_amdgcn_mfma_i32_32x32x32_i8(av1, bL, acc[1][0], 0, 0, 0); \
    acc[1][1] = __builtin_amdgcn_mfma_i32_32x32x32_i8(av1, bH, acc[1][1], 0, 0, 0); \
    __builtin_amdgcn_s_setprio(0); }

  DN_STAGE(0, 0);
  DN_STAGE(64, DN_BUF);

  const int NT = HID / 64;   // 172
  unsigned co = 0, so = 2 * DN_BUF;
  for (int kt = 0; kt < NT; ++kt) {
    if (kt + 2 < NT) {
      DN_STAGE((kt + 2) * 64, so);
      so = (so == 2 * DN_BUF) ? 0 : so + DN_BUF;
      asm volatile("s_waitcnt vmcnt(6)" ::: "memory");
    } else if (kt + 1 < NT) {
      asm volatile("s_waitcnt vmcnt(3)" ::: "memory");
    } else {
      asm volatile("s_waitcnt vmcnt(0)" ::: "memory");
    }
    __builtin_amdgcn_s_barrier();
    const char* sb = smem + co;
    DN_PHASE(0)
    DN_PHASE(1)
    __builtin_amdgcn_s_barrier();
    co = (co == 2 * DN_BUF) ? 0 : co + DN_BUF;
  }
  #undef DN_STAGE
  #undef DN_PHASE

  const int col = col0 + cf * 32 + (l & 31);
  #pragma unroll
  for (int m = 0; m < 2; ++m) {
    #pragma unroll
    for (int r = 0; r < 16; ++r) {
      const int row = row0 + rf * 64 + m * 32 + (r & 3) + 8 * (r >> 2) + 4 * (l >> 5);
      out[(size_t)row * DIMK + col] =
          (int)((((ll)acc[m][0][r] + ((ll)acc[m][1][r] << 7)) + 32768) >> 16);
    }
  }
}

// ============================================================
// Fallback (round-2 passing VALU kernels, used if ws too small)
// ============================================================
#define BT 64
#define BN 64
#define BK 64
#define LDST 68

__device__ __forceinline__ int mad24(int a, int b, int c) {
  return ((a << 8) >> 8) * ((b << 8) >> 8) + c;
}

__global__ __launch_bounds__(256)
void ffn_up_f(const int* __restrict__ x, const float* __restrict__ w1,
              const float* __restrict__ w3, short* __restrict__ t13)
{
  __shared__ int As[BT][LDST];
  __shared__ int B1[BK][LDST];
  __shared__ int B3[BK][LDST];
  const int tx = threadIdx.x, ty = threadIdx.y;
  const int tid = ty * 16 + tx;
  const int col0 = blockIdx.x * BN;
  const int row0 = blockIdx.y * BT;
  const int lr = tid >> 4;
  const int lk = (tid & 15) << 2;
  int acc1[16] = {0};
  int acc3[16] = {0};
  for (int k0 = 0; k0 < DIMK; k0 += BK) {
    #pragma unroll
    for (int m = 0; m < 4; ++m) {
      const int r = lr + m * 16;
      *reinterpret_cast<int4*>(&As[r][lk]) =
          *reinterpret_cast<const int4*>(&x[(size_t)(row0 + r) * DIMK + k0 + lk]);
      const float4 f1 = *reinterpret_cast<const float4*>(&w1[(size_t)(col0 + r) * DIMK + k0 + lk]);
      const float4 f3 = *reinterpret_cast<const float4*>(&w3[(size_t)(col0 + r) * DIMK + k0 + lk]);
      B1[lk + 0][r] = __float2int_rn(f1.x * 65536.0f);
      B1[lk + 1][r] = __float2int_rn(f1.y * 65536.0f);
      B1[lk + 2][r] = __float2int_rn(f1.z * 65536.0f);
      B1[lk + 3][r] = __float2int_rn(f1.w * 65536.0f);
      B3[lk + 0][r] = __float2int_rn(f3.x * 65536.0f);
      B3[lk + 1][r] = __float2int_rn(f3.y * 65536.0f);
      B3[lk + 2][r] = __float2int_rn(f3.z * 65536.0f);
      B3[lk + 3][r] = __float2int_rn(f3.w * 65536.0f);
    }
    __syncthreads();
    #pragma unroll 8
    for (int kk = 0; kk < BK; ++kk) {
      const int4 b1 = *reinterpret_cast<const int4*>(&B1[kk][tx << 2]);
      const int4 b3 = *reinterpret_cast<const int4*>(&B3[kk][tx << 2]);
      #pragma unroll
      for (int i = 0; i < 4; ++i) {
        const int av = As[(ty << 2) + i][kk] & 255;
        acc1[i*4+0] = mad24(av, b1.x, acc1[i*4+0]);
        acc1[i*4+1] = mad24(av, b1.y, acc1[i*4+1]);
        acc1[i*4+2] = mad24(av, b1.z, acc1[i*4+2]);
        acc1[i*4+3] = mad24(av, b1.w, acc1[i*4+3]);
        acc3[i*4+0] = mad24(av, b3.x, acc3[i*4+0]);
        acc3[i*4+1] = mad24(av, b3.y, acc3[i*4+1]);
        acc3[i*4+2] = mad24(av, b3.z, acc3[i*4+2]);
        acc3[i*4+3] = mad24(av, b3.w, acc3[i*4+3]);
      }
    }
    __syncthreads();
  }
  #pragma unroll
  for (int i = 0; i < 4; ++i) {
    #pragma unroll
    for (int j = 0; j < 4; ++j) {
      const int g    = (acc1[i*4+j] + 32768) >> 16;
      const int q3   = (acc3[i*4+j] + 32768) >> 16;
      const int gate = gate_requant(g);
      const int tv = (int)(((ll)gate * (ll)q3 + 32768) >> 16);
      t13[(size_t)(row0 + (ty<<2) + i) * HID + col0 + (tx<<2) + j] = (short)tv;
    }
  }
}

__global__ __launch_bounds__(256)
void ffn_down_f(const short* __restrict__ t13, const float* __restrict__ w2,
                int* __restrict__ out)
{
  __shared__ int As[BT][LDST];
  __shared__ int Bs[BK][LDST];
  const int tx = threadIdx.x, ty = threadIdx.y;
  const int tid = ty * 16 + tx;
  const int col0 = blockIdx.x * BN;
  const int row0 = blockIdx.y * BT;
  const int lr = tid >> 4;
  const int lk = (tid & 15) << 2;
  const int ar = tid >> 3;
  const int ak = (tid & 7) << 3;
  int acc[16] = {0};
  for (int k0 = 0; k0 < HID; k0 += BK) {
    #pragma unroll
    for (int m = 0; m < 2; ++m) {
      const int r = ar + m * 32;
      const int4 v = *reinterpret_cast<const int4*>(&t13[(size_t)(row0 + r) * HID + k0 + ak]);
      As[r][ak+0] = (v.x << 16) >> 16;  As[r][ak+1] = v.x >> 16;
      As[r][ak+2] = (v.y << 16) >> 16;  As[r][ak+3] = v.y >> 16;
      As[r][ak+4] = (v.z << 16) >> 16;  As[r][ak+5] = v.z >> 16;
      As[r][ak+6] = (v.w << 16) >> 16;  As[r][ak+7] = v.w >> 16;
    }
    #pragma unroll
    for (int m = 0; m < 4; ++m) {
      const int r = lr + m * 16;
      const float4 f = *reinterpret_cast<const float4*>(&w2[(size_t)(col0 + r) * HID + k0 + lk]);
      Bs[lk + 0][r] = __float2int_rn(f.x * 65536.0f);
      Bs[lk + 1][r] = __float2int_rn(f.y * 65536.0f);
      Bs[lk + 2][r] = __float2int_rn(f.z * 65536.0f);
      Bs[lk + 3][r] = __float2int_rn(f.w * 65536.0f);
    }
    __syncthreads();
    #pragma unroll 8
    for (int kk = 0; kk < BK; ++kk) {
      const int4 b = *reinterpret_cast<const int4*>(&Bs[kk][tx << 2]);
      #pragma unroll
      for (int i = 0; i < 4; ++i) {
        const int av = As[(ty << 2) + i][kk];
        acc[i*4+0] = mad24(av, b.x, acc[i*4+0]);
        acc[i*4+1] = mad24(av, b.y, acc[i*4+1]);
        acc[i*4+2] = mad24(av, b.z, acc[i*4+2]);
        acc[i*4+3] = mad24(av, b.w, acc[i*4+3]);
      }
    }
    __syncthreads();
  }
  #pragma unroll
  for (int i = 0; i < 4; ++i) {
    #pragma unroll
    for (int j = 0; j < 4; ++j) {
      out[(size_t)(row0 + (ty<<2) + i) * DIMK + col0 + (tx<<2) + j] =
          (acc[i*4+j] + 32768) >> 16;
    }
  }
}

// ============================================================
extern "C" void kernel_launch(void* const* d_in, const int* in_sizes, int n_in,
                              void* d_out, int out_size, void* d_ws, size_t ws_size,
                              hipStream_t stream) {
  (void)in_sizes; (void)n_in; (void)out_size;
  const int*   x  = (const int*)d_in[0];
  const float* w1 = (const float*)d_in[1];
  const float* w2 = (const float*)d_in[2];
  const float* w3 = (const float*)d_in[3];
  int* out = (int*)d_out;
  char* ws = (char*)d_ws;

  if (ws_size >= WS_NEED) {
    char* t13 = ws + T13_OFF;
    int*  lut = (int*)(ws + LUT_OFF);
    int*  cs1 = (int*)(ws + CS1_OFF);
    int*  cs3 = (int*)(ws + CS3_OFF);
    char* xq  = ws + XQ_OFF;
    char* wq  = ws + WQ_OFF;

    hipMemsetAsync(ws + CS1_OFF, 0, 88064, stream);
    hipLaunchKernelGGL(lut_kernel, dim3(32), dim3(256), 0, stream, lut);
    hipLaunchKernelGGL(xq_kernel, dim3(1024), dim3(256), 0, stream, x, xq);
    hipLaunchKernelGGL(prequant_all, dim3(33024), dim3(256), 0, stream,
                       w1, w3, w2, wq, cs1, cs3);
    hipLaunchKernelGGL(up_gemm, dim3(688), dim3(512), 0, stream,
                       xq, wq, cs1, cs3, lut, t13);
    hipLaunchKernelGGL(down_gemm, dim3(256), dim3(512), 0, stream,
                       t13, wq + 4 * PLANE, wq + 5 * PLANE, out);
  } else {
    if (ws_size < (size_t)TOK * HID * sizeof(short)) return;
    short* t13 = (short*)ws;
    dim3 blk(16, 16);
    hipLaunchKernelGGL(ffn_up_f,   dim3(HID / BN, TOK / BT), blk, 0, stream, x, w1, w3, t13);
    hipLaunchKernelGGL(ffn_down_f, dim3(DIMK / BN, TOK / BT), blk, 0, stream, t13, w2, out);
  }
}

// Round 7
// 515.518 us; speedup vs baseline: 11.9991x; 1.1214x over previous
//
#include <hip/hip_runtime.h>
#include <hip/hip_fp16.h>
#include <math.h>

#define TOK  1024
#define DIMK 4096
#define HID  11008

typedef long long ll;
typedef int v4i  __attribute__((ext_vector_type(4)));
typedef int v16i __attribute__((ext_vector_type(16)));

// ---------- ws layout ----------
#define T13_OFF 0ull
#define LUT_OFF 11272192ull
#define CS1_OFF (LUT_OFF + 32768ull)
#define CS3_OFF (CS1_OFF + 44032ull)
#define XQ_OFF  (CS3_OFF + 44032ull)
#define WQ_OFF  (XQ_OFF + 4194304ull)
#define PLANE   45088768ull                          // 11008*4096 bytes
#define WS_NEED (WQ_OFF + 6ull * PLANE)              // ~273 MB

// ---------- exact fp16-silu requant (proven in round 2) ----------
__device__ __forceinline__ int gate_requant(int g) {
  const float vf = __half2float(__float2half((float)g * (1.0f / 65536.0f)));
  const float e32 = (float)exp(-(double)vf);
  const float e16 = __half2float(__float2half(e32));
  const float d16 = __half2float(__float2half(1.0f + e16));
  const float s16 = __half2float(__float2half(1.0f / d16));
  const float p16 = __half2float(__float2half(vf * s16));
  return __float2int_rn(p16 * 65536.0f);
}

__device__ __forceinline__ v16i vzero16() {
  v16i z;
  #pragma unroll
  for (int i = 0; i < 16; ++i) z[i] = 0;
  return z;
}

// async global->LDS, 16B per lane; lds ptr must be wave-uniform
__device__ __forceinline__ void gll(const void* g, void* l) {
  __builtin_amdgcn_global_load_lds((const __attribute__((address_space(1))) unsigned int*)g,
                                   (__attribute__((address_space(3))) unsigned int*)l,
                                   16, 0, 0);
}

// ============================================================
// Pre-pass kernels
// ============================================================

__global__ void lut_kernel(int* __restrict__ lut) {
  const int i = blockIdx.x * blockDim.x + threadIdx.x;   // 0..8191
  lut[i] = gate_requant(i - 4096);
}

// xq = (i8)(x - 128), packed bytes
__global__ __launch_bounds__(256)
void xq_kernel(const int* __restrict__ x, char* __restrict__ xq) {
  const size_t base = ((size_t)blockIdx.x * 256 + threadIdx.x) * 16;
  int w[4];
  #pragma unroll
  for (int i = 0; i < 4; ++i) {
    const int4 v = *reinterpret_cast<const int4*>(&x[base + i * 4]);
    w[i] = ((v.x & 255) | ((v.y & 255) << 8) | ((v.z & 255) << 16) | ((v.w & 255) << 24)) ^ 0x80808080;
  }
  *reinterpret_cast<int4*>(&xq[base]) = make_int4(w[0], w[1], w[2], w[3]);
}

// All three weight matrices in one dispatch; fully coalesced.
__global__ __launch_bounds__(256)
void prequant_all(const float* __restrict__ w1, const float* __restrict__ w3,
                  const float* __restrict__ w2, char* __restrict__ wq,
                  int* __restrict__ cs1, int* __restrict__ cs3)
{
  const int bid = blockIdx.x;
  const int m = bid / 11008;            // 0,1,2 (uniform per block)
  const int rb = bid - m * 11008;
  const float* src = (m == 0) ? w1 : ((m == 1) ? w3 : w2);
  int* lo = (int*)(wq + (size_t)(2 * m) * PLANE);
  int* hi = (int*)(wq + (size_t)(2 * m + 1) * PLANE);
  const size_t f4base = (size_t)rb * 1024;

  int sum = 0;
  #pragma unroll
  for (int j = 0; j < 4; ++j) {
    const size_t f4 = f4base + threadIdx.x + j * 256;
    const float4 f = *reinterpret_cast<const float4*>(&src[f4 * 4]);
    const int q0 = __float2int_rn(f.x * 65536.0f);
    const int q1 = __float2int_rn(f.y * 65536.0f);
    const int q2 = __float2int_rn(f.z * 65536.0f);
    const int q3 = __float2int_rn(f.w * 65536.0f);
    sum += q0 + q1 + q2 + q3;
    lo[f4] = (q0 & 127) | ((q1 & 127) << 8) | ((q2 & 127) << 16) | ((q3 & 127) << 24);
    hi[f4] = ((q0 >> 7) & 255) | (((q1 >> 7) & 255) << 8) |
             (((q2 >> 7) & 255) << 16) | (((q3 >> 7) & 255) << 24);
  }
  if (m < 2) {
    #pragma unroll
    for (int off = 32; off > 0; off >>= 1) sum += __shfl_xor(sum, off, 64);
    if ((threadIdx.x & 63) == 0) atomicAdd(((m == 0) ? cs1 : cs3) + rb, sum);
  }
}

// ============================================================
// Up GEMM: BT=256 rows, BN=64 cols, 4 planes, BK=64; 512 thr = 8 waves.
// m201-style schedule: per K-tile 2 phases; per phase:
//   {6 ds_read (issued pre-barrier) | 2 gll stage of kt+2 -> s_barrier ->
//    lgkmcnt(0)+sched_barrier -> setprio(1) 8xMFMA setprio(0) -> s_barrier}
// vmcnt counted once per tile (4 in flight). Triple buffer 3x32KB.
// ============================================================
#define UP_BUF 32768

__global__ __launch_bounds__(512, 1)
void up_gemm(const char* __restrict__ xq, const char* __restrict__ wq,
             const int* __restrict__ csum1, const int* __restrict__ csum3,
             const int* __restrict__ lut, char* __restrict__ t13)
{
  __shared__ char smem[3 * UP_BUF];
  const int tid = threadIdx.x;
  const int w = tid >> 6, l = tid & 63;
  const int rf = w & 3, cf = w >> 2;
  const int l16 = l * 16;

  // bijective XCD swizzle: 688 = 8 * 86
  const int flat = blockIdx.x;
  const int g = (flat & 7) * 86 + (flat >> 3);
  const int col0 = (g >> 2) * 64;
  const int row0 = (g & 3) * 256;

  // staging (wave w): A segs {2w,2w+1} (rows w*32..+32, ks=0/1), B segs
  // {2w,2w+1} (plane=w>>1, colhalf=w&1, ks=0/1). 1KB segs; A 0..16K, B 16K..32K.
  const char* gA = xq + (size_t)(row0 + w * 32 + (l & 31)) * DIMK + (l >> 5) * 16;
  const char* gB = wq + (size_t)(w >> 1) * PLANE
                 + (size_t)(col0 + (w & 1) * 32 + (l & 31)) * DIMK + (l >> 5) * 16;
  const unsigned dA0 = (2 * w + 0) * 1024, dA1 = (2 * w + 1) * 1024;
  const unsigned dB0 = 16384 + (2 * w + 0) * 1024, dB1 = 16384 + (2 * w + 1) * 1024;

  v16i acc[2][4];
  #pragma unroll
  for (int m = 0; m < 2; ++m)
    #pragma unroll
    for (int p = 0; p < 4; ++p) acc[m][p] = vzero16();

  // prologue: stage tiles 0 and 1; wait tile 0
  gll(gA, smem + dA0);       gll(gA + 32, smem + dA1);
  gll(gB, smem + dB0);       gll(gB + 32, smem + dB1);
  gll(gA + 64, smem + UP_BUF + dA0);  gll(gA + 96, smem + UP_BUF + dA1);
  gll(gB + 64, smem + UP_BUF + dB0);  gll(gB + 96, smem + UP_BUF + dB1);
  asm volatile("s_waitcnt vmcnt(4)" ::: "memory");
  __builtin_amdgcn_s_barrier();

  const int NT = DIMK / 64;
  unsigned co = 0, so = 2 * UP_BUF;
  for (int kt = 0; kt < NT; ++kt) {
    const char* sb = smem + co;
    const bool st = (kt + 2 < NT);
    const int kb = (kt + 2) * 64;
    // ---------------- phase 0 (ks = 0) ----------------
    {
      const v4i av0 = *(const v4i*)(sb + (rf * 4 + 0) * 1024 + l16);
      const v4i av1 = *(const v4i*)(sb + (rf * 4 + 2) * 1024 + l16);
      const v4i b0  = *(const v4i*)(sb + 16384 + (0 * 4 + cf * 2) * 1024 + l16);
      const v4i b1  = *(const v4i*)(sb + 16384 + (1 * 4 + cf * 2) * 1024 + l16);
      const v4i b2  = *(const v4i*)(sb + 16384 + (2 * 4 + cf * 2) * 1024 + l16);
      const v4i b3  = *(const v4i*)(sb + 16384 + (3 * 4 + cf * 2) * 1024 + l16);
      if (st) { gll(gA + kb, smem + so + dA0); gll(gA + kb + 32, smem + so + dA1); }
      __builtin_amdgcn_s_barrier();
      asm volatile("s_waitcnt lgkmcnt(0)" ::: "memory");
      __builtin_amdgcn_sched_barrier(0);
      __builtin_amdgcn_s_setprio(1);
      acc[0][0] = __builtin_amdgcn_mfma_i32_32x32x32_i8(av0, b0, acc[0][0], 0, 0, 0);
      acc[0][1] = __builtin_amdgcn_mfma_i32_32x32x32_i8(av0, b1, acc[0][1], 0, 0, 0);
      acc[0][2] = __builtin_amdgcn_mfma_i32_32x32x32_i8(av0, b2, acc[0][2], 0, 0, 0);
      acc[0][3] = __builtin_amdgcn_mfma_i32_32x32x32_i8(av0, b3, acc[0][3], 0, 0, 0);
      acc[1][0] = __builtin_amdgcn_mfma_i32_32x32x32_i8(av1, b0, acc[1][0], 0, 0, 0);
      acc[1][1] = __builtin_amdgcn_mfma_i32_32x32x32_i8(av1, b1, acc[1][1], 0, 0, 0);
      acc[1][2] = __builtin_amdgcn_mfma_i32_32x32x32_i8(av1, b2, acc[1][2], 0, 0, 0);
      acc[1][3] = __builtin_amdgcn_mfma_i32_32x32x32_i8(av1, b3, acc[1][3], 0, 0, 0);
      __builtin_amdgcn_s_setprio(0);
      __builtin_amdgcn_s_barrier();
    }
    // ---------------- phase 1 (ks = 1) ----------------
    {
      const v4i av0 = *(const v4i*)(sb + (rf * 4 + 1) * 1024 + l16);
      const v4i av1 = *(const v4i*)(sb + (rf * 4 + 3) * 1024 + l16);
      const v4i b0  = *(const v4i*)(sb + 16384 + (0 * 4 + cf * 2 + 1) * 1024 + l16);
      const v4i b1  = *(const v4i*)(sb + 16384 + (1 * 4 + cf * 2 + 1) * 1024 + l16);
      const v4i b2  = *(const v4i*)(sb + 16384 + (2 * 4 + cf * 2 + 1) * 1024 + l16);
      const v4i b3  = *(const v4i*)(sb + 16384 + (3 * 4 + cf * 2 + 1) * 1024 + l16);
      if (st) { gll(gB + kb, smem + so + dB0); gll(gB + kb + 32, smem + so + dB1); }
      __builtin_amdgcn_s_barrier();
      asm volatile("s_waitcnt lgkmcnt(0)" ::: "memory");
      __builtin_amdgcn_sched_barrier(0);
      __builtin_amdgcn_s_setprio(1);
      acc[0][0] = __builtin_amdgcn_mfma_i32_32x32x32_i8(av0, b0, acc[0][0], 0, 0, 0);
      acc[0][1] = __builtin_amdgcn_mfma_i32_32x32x32_i8(av0, b1, acc[0][1], 0, 0, 0);
      acc[0][2] = __builtin_amdgcn_mfma_i32_32x32x32_i8(av0, b2, acc[0][2], 0, 0, 0);
      acc[0][3] = __builtin_amdgcn_mfma_i32_32x32x32_i8(av0, b3, acc[0][3], 0, 0, 0);
      acc[1][0] = __builtin_amdgcn_mfma_i32_32x32x32_i8(av1, b0, acc[1][0], 0, 0, 0);
      acc[1][1] = __builtin_amdgcn_mfma_i32_32x32x32_i8(av1, b1, acc[1][1], 0, 0, 0);
      acc[1][2] = __builtin_amdgcn_mfma_i32_32x32x32_i8(av1, b2, acc[1][2], 0, 0, 0);
      acc[1][3] = __builtin_amdgcn_mfma_i32_32x32x32_i8(av1, b3, acc[1][3], 0, 0, 0);
      __builtin_amdgcn_s_setprio(0);
      if (st) { asm volatile("s_waitcnt vmcnt(4)" ::: "memory"); }
      else    { asm volatile("s_waitcnt vmcnt(0)" ::: "memory"); }
      __builtin_amdgcn_s_barrier();
    }
    if (st) so = (so == 2 * UP_BUF) ? 0 : so + UP_BUF;
    co = (co == 2 * UP_BUF) ? 0 : co + UP_BUF;
  }

  const int col = col0 + cf * 32 + (l & 31);
  const int cs1v = csum1[col], cs3v = csum3[col];
  #pragma unroll
  for (int m = 0; m < 2; ++m) {
    #pragma unroll
    for (int r = 0; r < 16; ++r) {
      const int row = row0 + rf * 64 + m * 32 + (r & 3) + 8 * (r >> 2) + 4 * (l >> 5);
      const ll t1 = (ll)acc[m][0][r] + (((ll)acc[m][1][r] + cs1v) << 7);
      int gg = (int)((t1 + 32768) >> 16);
      gg = gg < -4096 ? -4096 : (gg > 4095 ? 4095 : gg);
      const ll t3 = (ll)acc[m][2][r] + (((ll)acc[m][3][r] + cs3v) << 7);
      const int q3 = (int)((t3 + 32768) >> 16);
      const int gate = lut[gg + 4096];
      t13[(size_t)row * HID + col] = (char)((int)(((ll)gate * q3 + 32768) >> 16));
    }
  }
}

// ============================================================
// Down GEMM: BT=256, BN=64, 2 planes, BK=64 over HID; 512 thr = 8 waves.
// Same m201-style per-phase schedule. Triple buffer 3x24KB, grid 256 = 1/CU.
// ============================================================
#define DN_BUF 24576

__global__ __launch_bounds__(512, 1)
void down_gemm(const char* __restrict__ t13, const char* __restrict__ w2lo,
               const char* __restrict__ w2hi, int* __restrict__ out)
{
  __shared__ char smem[3 * DN_BUF];
  const int tid = threadIdx.x;
  const int w = tid >> 6, l = tid & 63;
  const int rf = w & 3, cf = w >> 2;
  const int l16 = l * 16;

  // bijective XCD swizzle: 256 = 8 * 32
  const int flat = blockIdx.x;
  const int g = (flat & 7) * 32 + (flat >> 3);
  const int col0 = (g >> 2) * 64;
  const int row0 = (g & 3) * 256;

  const char* gA = t13 + (size_t)(row0 + w * 32 + (l & 31)) * HID + (l >> 5) * 16;
  const char* pB = (w >> 2) ? w2hi : w2lo;
  const char* gB = pB + (size_t)(col0 + ((w >> 1) & 1) * 32 + (l & 31)) * HID
                 + (w & 1) * 32 + (l >> 5) * 16;
  const unsigned dA0 = (2 * w + 0) * 1024, dA1 = (2 * w + 1) * 1024;
  const unsigned dB = 16384 + w * 1024;

  v16i acc[2][2];
  #pragma unroll
  for (int m = 0; m < 2; ++m)
    #pragma unroll
    for (int p = 0; p < 2; ++p) acc[m][p] = vzero16();

  // prologue: tiles 0,1 (3 gll each); wait tile 0
  gll(gA, smem + dA0);  gll(gA + 32, smem + dA1);  gll(gB, smem + dB);
  gll(gA + 64, smem + DN_BUF + dA0);  gll(gA + 96, smem + DN_BUF + dA1);
  gll(gB + 64, smem + DN_BUF + dB);
  asm volatile("s_waitcnt vmcnt(3)" ::: "memory");
  __builtin_amdgcn_s_barrier();

  const int NT = HID / 64;   // 172
  unsigned co = 0, so = 2 * DN_BUF;
  for (int kt = 0; kt < NT; ++kt) {
    const char* sb = smem + co;
    const bool st = (kt + 2 < NT);
    const int kb = (kt + 2) * 64;
    // ---------------- phase 0 (ks = 0) ----------------
    {
      const v4i av0 = *(const v4i*)(sb + (rf * 4 + 0) * 1024 + l16);
      const v4i av1 = *(const v4i*)(sb + (rf * 4 + 2) * 1024 + l16);
      const v4i bL  = *(const v4i*)(sb + 16384 + (0 * 4 + cf * 2) * 1024 + l16);
      const v4i bH  = *(const v4i*)(sb + 16384 + (1 * 4 + cf * 2) * 1024 + l16);
      if (st) { gll(gA + kb, smem + so + dA0); gll(gA + kb + 32, smem + so + dA1); }
      __builtin_amdgcn_s_barrier();
      asm volatile("s_waitcnt lgkmcnt(0)" ::: "memory");
      __builtin_amdgcn_sched_barrier(0);
      __builtin_amdgcn_s_setprio(1);
      acc[0][0] = __builtin_amdgcn_mfma_i32_32x32x32_i8(av0, bL, acc[0][0], 0, 0, 0);
      acc[0][1] = __builtin_amdgcn_mfma_i32_32x32x32_i8(av0, bH, acc[0][1], 0, 0, 0);
      acc[1][0] = __builtin_amdgcn_mfma_i32_32x32x32_i8(av1, bL, acc[1][0], 0, 0, 0);
      acc[1][1] = __builtin_amdgcn_mfma_i32_32x32x32_i8(av1, bH, acc[1][1], 0, 0, 0);
      __builtin_amdgcn_s_setprio(0);
      __builtin_amdgcn_s_barrier();
    }
    // ---------------- phase 1 (ks = 1) ----------------
    {
      const v4i av0 = *(const v4i*)(sb + (rf * 4 + 1) * 1024 + l16);
      const v4i av1 = *(const v4i*)(sb + (rf * 4 + 3) * 1024 + l16);
      const v4i bL  = *(const v4i*)(sb + 16384 + (0 * 4 + cf * 2 + 1) * 1024 + l16);
      const v4i bH  = *(const v4i*)(sb + 16384 + (1 * 4 + cf * 2 + 1) * 1024 + l16);
      if (st) { gll(gB + kb, smem + so + dB); }
      __builtin_amdgcn_s_barrier();
      asm volatile("s_waitcnt lgkmcnt(0)" ::: "memory");
      __builtin_amdgcn_sched_barrier(0);
      __builtin_amdgcn_s_setprio(1);
      acc[0][0] = __builtin_amdgcn_mfma_i32_32x32x32_i8(av0, bL, acc[0][0], 0, 0, 0);
      acc[0][1] = __builtin_amdgcn_mfma_i32_32x32x32_i8(av0, bH, acc[0][1], 0, 0, 0);
      acc[1][0] = __builtin_amdgcn_mfma_i32_32x32x32_i8(av1, bL, acc[1][0], 0, 0, 0);
      acc[1][1] = __builtin_amdgcn_mfma_i32_32x32x32_i8(av1, bH, acc[1][1], 0, 0, 0);
      __builtin_amdgcn_s_setprio(0);
      if (st) { asm volatile("s_waitcnt vmcnt(3)" ::: "memory"); }
      else    { asm volatile("s_waitcnt vmcnt(0)" ::: "memory"); }
      __builtin_amdgcn_s_barrier();
    }
    if (st) so = (so == 2 * DN_BUF) ? 0 : so + DN_BUF;
    co = (co == 2 * DN_BUF) ? 0 : co + DN_BUF;
  }

  const int col = col0 + cf * 32 + (l & 31);
  #pragma unroll
  for (int m = 0; m < 2; ++m) {
    #pragma unroll
    for (int r = 0; r < 16; ++r) {
      const int row = row0 + rf * 64 + m * 32 + (r & 3) + 8 * (r >> 2) + 4 * (l >> 5);
      out[(size_t)row * DIMK + col] =
          (int)((((ll)acc[m][0][r] + ((ll)acc[m][1][r] << 7)) + 32768) >> 16);
    }
  }
}

// ============================================================
// Fallback (round-2 passing VALU kernels, used if ws too small)
// ============================================================
#define BT 64
#define BN 64
#define BK 64
#define LDST 68

__device__ __forceinline__ int mad24(int a, int b, int c) {
  return ((a << 8) >> 8) * ((b << 8) >> 8) + c;
}

__global__ __launch_bounds__(256)
void ffn_up_f(const int* __restrict__ x, const float* __restrict__ w1,
              const float* __restrict__ w3, short* __restrict__ t13)
{
  __shared__ int As[BT][LDST];
  __shared__ int B1[BK][LDST];
  __shared__ int B3[BK][LDST];
  const int tx = threadIdx.x, ty = threadIdx.y;
  const int tid = ty * 16 + tx;
  const int col0 = blockIdx.x * BN;
  const int row0 = blockIdx.y * BT;
  const int lr = tid >> 4;
  const int lk = (tid & 15) << 2;
  int acc1[16] = {0};
  int acc3[16] = {0};
  for (int k0 = 0; k0 < DIMK; k0 += BK) {
    #pragma unroll
    for (int m = 0; m < 4; ++m) {
      const int r = lr + m * 16;
      *reinterpret_cast<int4*>(&As[r][lk]) =
          *reinterpret_cast<const int4*>(&x[(size_t)(row0 + r) * DIMK + k0 + lk]);
      const float4 f1 = *reinterpret_cast<const float4*>(&w1[(size_t)(col0 + r) * DIMK + k0 + lk]);
      const float4 f3 = *reinterpret_cast<const float4*>(&w3[(size_t)(col0 + r) * DIMK + k0 + lk]);
      B1[lk + 0][r] = __float2int_rn(f1.x * 65536.0f);
      B1[lk + 1][r] = __float2int_rn(f1.y * 65536.0f);
      B1[lk + 2][r] = __float2int_rn(f1.z * 65536.0f);
      B1[lk + 3][r] = __float2int_rn(f1.w * 65536.0f);
      B3[lk + 0][r] = __float2int_rn(f3.x * 65536.0f);
      B3[lk + 1][r] = __float2int_rn(f3.y * 65536.0f);
      B3[lk + 2][r] = __float2int_rn(f3.z * 65536.0f);
      B3[lk + 3][r] = __float2int_rn(f3.w * 65536.0f);
    }
    __syncthreads();
    #pragma unroll 8
    for (int kk = 0; kk < BK; ++kk) {
      const int4 b1 = *reinterpret_cast<const int4*>(&B1[kk][tx << 2]);
      const int4 b3 = *reinterpret_cast<const int4*>(&B3[kk][tx << 2]);
      #pragma unroll
      for (int i = 0; i < 4; ++i) {
        const int av = As[(ty << 2) + i][kk] & 255;
        acc1[i*4+0] = mad24(av, b1.x, acc1[i*4+0]);
        acc1[i*4+1] = mad24(av, b1.y, acc1[i*4+1]);
        acc1[i*4+2] = mad24(av, b1.z, acc1[i*4+2]);
        acc1[i*4+3] = mad24(av, b1.w, acc1[i*4+3]);
        acc3[i*4+0] = mad24(av, b3.x, acc3[i*4+0]);
        acc3[i*4+1] = mad24(av, b3.y, acc3[i*4+1]);
        acc3[i*4+2] = mad24(av, b3.z, acc3[i*4+2]);
        acc3[i*4+3] = mad24(av, b3.w, acc3[i*4+3]);
      }
    }
    __syncthreads();
  }
  #pragma unroll
  for (int i = 0; i < 4; ++i) {
    #pragma unroll
    for (int j = 0; j < 4; ++j) {
      const int g    = (acc1[i*4+j] + 32768) >> 16;
      const int q3   = (acc3[i*4+j] + 32768) >> 16;
      const int gate = gate_requant(g);
      const int tv = (int)(((ll)gate * (ll)q3 + 32768) >> 16);
      t13[(size_t)(row0 + (ty<<2) + i) * HID + col0 + (tx<<2) + j] = (short)tv;
    }
  }
}

__global__ __launch_bounds__(256)
void ffn_down_f(const short* __restrict__ t13, const float* __restrict__ w2,
                int* __restrict__ out)
{
  __shared__ int As[BT][LDST];
  __shared__ int Bs[BK][LDST];
  const int tx = threadIdx.x, ty = threadIdx.y;
  const int tid = ty * 16 + tx;
  const int col0 = blockIdx.x * BN;
  const int row0 = blockIdx.y * BT;
  const int lr = tid >> 4;
  const int lk = (tid & 15) << 2;
  const int ar = tid >> 3;
  const int ak = (tid & 7) << 3;
  int acc[16] = {0};
  for (int k0 = 0; k0 < HID; k0 += BK) {
    #pragma unroll
    for (int m = 0; m < 2; ++m) {
      const int r = ar + m * 32;
      const int4 v = *reinterpret_cast<const int4*>(&t13[(size_t)(row0 + r) * HID + k0 + ak]);
      As[r][ak+0] = (v.x << 16) >> 16;  As[r][ak+1] = v.x >> 16;
      As[r][ak+2] = (v.y << 16) >> 16;  As[r][ak+3] = v.y >> 16;
      As[r][ak+4] = (v.z << 16) >> 16;  As[r][ak+5] = v.z >> 16;
      As[r][ak+6] = (v.w << 16) >> 16;  As[r][ak+7] = v.w >> 16;
    }
    #pragma unroll
    for (int m = 0; m < 4; ++m) {
      const int r = lr + m * 16;
      const float4 f = *reinterpret_cast<const float4*>(&w2[(size_t)(col0 + r) * HID + k0 + lk]);
      Bs[lk + 0][r] = __float2int_rn(f.x * 65536.0f);
      Bs[lk + 1][r] = __float2int_rn(f.y * 65536.0f);
      Bs[lk + 2][r] = __float2int_rn(f.z * 65536.0f);
      Bs[lk + 3][r] = __float2int_rn(f.w * 65536.0f);
    }
    __syncthreads();
    #pragma unroll 8
    for (int kk = 0; kk < BK; ++kk) {
      const int4 b = *reinterpret_cast<const int4*>(&Bs[kk][tx << 2]);
      #pragma unroll
      for (int i = 0; i < 4; ++i) {
        const int av = As[(ty << 2) + i][kk];
        acc[i*4+0] = mad24(av, b.x, acc[i*4+0]);
        acc[i*4+1] = mad24(av, b.y, acc[i*4+1]);
        acc[i*4+2] = mad24(av, b.z, acc[i*4+2]);
        acc[i*4+3] = mad24(av, b.w, acc[i*4+3]);
      }
    }
    __syncthreads();
  }
  #pragma unroll
  for (int i = 0; i < 4; ++i) {
    #pragma unroll
    for (int j = 0; j < 4; ++j) {
      out[(size_t)(row0 + (ty<<2) + i) * DIMK + col0 + (tx<<2) + j] =
          (acc[i*4+j] + 32768) >> 16;
    }
  }
}

// ============================================================
extern "C" void kernel_launch(void* const* d_in, const int* in_sizes, int n_in,
                              void* d_out, int out_size, void* d_ws, size_t ws_size,
                              hipStream_t stream) {
  (void)in_sizes; (void)n_in; (void)out_size;
  const int*   x  = (const int*)d_in[0];
  const float* w1 = (const float*)d_in[1];
  const float* w2 = (const float*)d_in[2];
  const float* w3 = (const float*)d_in[3];
  int* out = (int*)d_out;
  char* ws = (char*)d_ws;

  if (ws_size >= WS_NEED) {
    char* t13 = ws + T13_OFF;
    int*  lut = (int*)(ws + LUT_OFF);
    int*  cs1 = (int*)(ws + CS1_OFF);
    int*  cs3 = (int*)(ws + CS3_OFF);
    char* xq  = ws + XQ_OFF;
    char* wq  = ws + WQ_OFF;

    hipMemsetAsync(ws + CS1_OFF, 0, 88064, stream);
    hipLaunchKernelGGL(lut_kernel, dim3(32), dim3(256), 0, stream, lut);
    hipLaunchKernelGGL(xq_kernel, dim3(1024), dim3(256), 0, stream, x, xq);
    hipLaunchKernelGGL(prequant_all, dim3(33024), dim3(256), 0, stream,
                       w1, w3, w2, wq, cs1, cs3);
    hipLaunchKernelGGL(up_gemm, dim3(688), dim3(512), 0, stream,
                       xq, wq, cs1, cs3, lut, t13);
    hipLaunchKernelGGL(down_gemm, dim3(256), dim3(512), 0, stream,
                       t13, wq + 4 * PLANE, wq + 5 * PLANE, out);
  } else {
    if (ws_size < (size_t)TOK * HID * sizeof(short)) return;
    short* t13 = (short*)ws;
    dim3 blk(16, 16);
    hipLaunchKernelGGL(ffn_up_f,   dim3(HID / BN, TOK / BT), blk, 0, stream, x, w1, w3, t13);
    hipLaunchKernelGGL(ffn_down_f, dim3(DIMK / BN, TOK / BT), blk, 0, stream, t13, w2, out);
  }
}